// Round 7
// baseline (1189.672 us; speedup 1.0000x reference)
//
#include <hip/hip_runtime.h>

// ---------------- problem constants ----------------
#define T_TOKENS 8192
#define H_DIM    2048
#define I_DIM    4096
#define NE       8
#define NPAIR    16384                  // T_TOKENS * TOP_K
#define PADBM    256                    // expert segment padding (= BM of GEMM tiles)
#define PADP     (NPAIR + NE * PADBM)   // 18432 worst-case padded rows
#define RT_MAX   (PADP / PADBM)         // 72 max row tiles (72 = 9*8, XCD-exact)

// 256x256x64 8-phase GEMM geometry
#define BM2 256
#define BN2 256
#define BK2 64
#define NTHR 512
#define NKT_UP (H_DIM / BK2)            // 32
#define NKT_DN (I_DIM / BK2)            // 64
#define NTN_UP (I_DIM / BN2)            // 16
#define NTN_DN (H_DIM / BN2)            // 8
#define TILE_B 32768                    // bytes per 256x64 bf16 operand tile
#define TILE_S 16384                    // shorts per tile

// ---------------- workspace layout (bytes) ----------------
// Ab (tiled gathered x) 75.5MB  [reused as Yb 67MB after gemm_up]
// Wt (tiled weights)   134.2MB  [up -> down]
// Hb (tiled)           151.0MB
// tok 74KB | meta 128B            total ~361MB
#define WS_AB   0ull
#define WS_W    (WS_AB + (size_t)RT_MAX * NKT_UP * TILE_B)
#define WS_H    (WS_W + (size_t)NE * I_DIM * H_DIM * 2)
#define WS_TOK  (WS_H + (size_t)RT_MAX * NKT_DN * TILE_B)
#define WS_META (WS_TOK + (size_t)PADP * 4)

typedef __attribute__((ext_vector_type(8))) short bf16x8;   // 8 bf16 = 4 VGPRs
typedef __attribute__((ext_vector_type(4))) float f32x4;    // MFMA C/D

__device__ __forceinline__ unsigned short f2bf(float f) {
  union { float f; unsigned u; } a; a.f = f;
  unsigned r = a.u + 0x7fffu + ((a.u >> 16) & 1u);   // RNE
  return (unsigned short)(r >> 16);
}

__device__ __forceinline__ float b2f(unsigned short b) {
  union { unsigned u; float f; } a; a.u = ((unsigned)b) << 16;
  return a.f;
}

__device__ __forceinline__ bf16x8 pack8(float4 a, float4 b) {
  bf16x8 o;
  o[0] = (short)f2bf(a.x); o[1] = (short)f2bf(a.y);
  o[2] = (short)f2bf(a.z); o[3] = (short)f2bf(a.w);
  o[4] = (short)f2bf(b.x); o[5] = (short)f2bf(b.y);
  o[6] = (short)f2bf(b.z); o[7] = (short)f2bf(b.w);
  return o;
}

__device__ __forceinline__ void gload16(const void* g, void* l) {
  __builtin_amdgcn_global_load_lds(
      (const __attribute__((address_space(1))) unsigned int*)g,
      (__attribute__((address_space(3))) unsigned int*)l,
      16, 0, 0);
}

// ---------------- routing: single-block count/scan/scatter + tok init ----------------
__global__ __launch_bounds__(512) void route_all(const int* __restrict__ idx,
                                                 int* __restrict__ meta,
                                                 int* __restrict__ tok) {
  __shared__ int cnt[NE], base[NE + 1], cur[NE];
  int t = threadIdx.x;
  if (t < NE) { cnt[t] = 0; cur[t] = 0; }
  for (int i = t; i < PADP; i += 512) tok[i] = -1;   // -1 = padding
  __syncthreads();
  for (int i = t; i < NPAIR; i += 512) atomicAdd(&cnt[idx[i]], 1);
  __syncthreads();
  if (t == 0) {
    int off = 0;
    for (int e = 0; e < NE; ++e) {
      base[e] = off;
      off += ((cnt[e] + PADBM - 1) / PADBM) * PADBM;
    }
    base[NE] = off;
    for (int e = 0; e <= NE; ++e) meta[16 + e] = base[e];
  }
  __syncthreads();
  for (int i = t; i < NPAIR; i += 512) {
    int e = idx[i];
    int pos = base[e] + atomicAdd(&cur[e], 1);
    tok[pos] = i;                       // pair index; token = i>>1 (TOP_K=2)
  }
}

// ---------------- weight fp32 -> tiled bf16 (linear coalesced reads) ----------------
// Block: 8 rows x K of one 256-row panel. Reads are perfectly linear; the tiled
// destination [panel][kt][c][r][8] is computed from the linear float index.
__global__ __launch_bounds__(512) void cvt_tile_w(
    const float* __restrict__ W, unsigned short* __restrict__ out,
    int NKT, int kshift) {
  int b = blockIdx.x;
  int panel = b >> 5, r0 = (b & 31) * 8;           // 32 blocks per 256-row panel
  const float* src = W + (((size_t)panel * 256 + r0) << kshift);
  unsigned short* dstp = out + (size_t)panel * NKT * TILE_S;
  int K1 = (1 << kshift) - 1;
  int iters = 1 << (kshift - 9);                   // 8*K/4096
  for (int it = 0; it < iters; ++it) {
    int f = it * 4096 + threadIdx.x * 8;           // linear float idx in 8xK block
    float4 v0 = *(const float4*)(src + f);
    float4 v1 = *(const float4*)(src + f + 4);
    int r = f >> kshift, k = f & K1;
    int kt = k >> 6, c = (k >> 3) & 7;
    *(bf16x8*)(dstp + (size_t)kt * TILE_S + c * 2048 + (r0 + r) * 8) = pack8(v0, v1);
  }
}

// ---------------- gathered x fp32 -> tiled bf16 A (row-granule gather) ----------------
// Block: 32 rows x H_DIM of one rt tile; 16 threads/row -> 512B row segments.
__global__ __launch_bounds__(512) void gather_tile_x(
    const float* __restrict__ x, const int* __restrict__ tok,
    unsigned short* __restrict__ out) {
  int b = blockIdx.x;
  int rt = b >> 3, r0 = (b & 7) * 32;
  int t = threadIdx.x;
  int r = r0 + (t >> 4), c16 = t & 15;
  int v = tok[rt * 256 + r];
  unsigned short* dstp = out + (size_t)rt * NKT_UP * TILE_S + (size_t)r * 8;
  if (v < 0) {
    bf16x8 z = {};
    #pragma unroll
    for (int i = 0; i < 16; ++i) {
      int k = i * 128 + c16 * 8;
      *(bf16x8*)(dstp + (size_t)(k >> 6) * TILE_S + ((k >> 3) & 7) * 2048) = z;
    }
  } else {
    const float* src = x + (size_t)(v >> 1) * H_DIM;
    #pragma unroll
    for (int i = 0; i < 16; ++i) {
      int k = i * 128 + c16 * 8;
      float4 v0 = *(const float4*)(src + k);
      float4 v1 = *(const float4*)(src + k + 4);
      *(bf16x8*)(dstp + (size_t)(k >> 6) * TILE_S + ((k >> 3) & 7) * 2048) = pack8(v0, v1);
    }
  }
}

// ---------------- 8-phase 256^2 grouped-GEMM core (linear tiled staging) ----------------
// LDS: A dbuf [2][32KB] at 0; B dbuf at 65536. Stage = linear 32KB copy per operand.
// Per-thread issue order A,B per l_: first 4 done <=> ks=0 chunks of both staged.
// vmcnt(8)@c1 (tile t fully landed), vmcnt(4)@c3 (ks=0 of t+1 landed).
// Never drains to 0 in main loop.

#define STAGE_FULL(KT, BS) do {                                                \
    const char* aT_ = aTile + (size_t)(KT) * TILE_B;                           \
    const char* bT_ = bTile + (size_t)(KT) * TILE_B;                           \
    _Pragma("unroll")                                                          \
    for (int l_ = 0; l_ < 4; ++l_) {                                           \
      int off_ = (l_ * 8 + wv) * 1024 + lane16;                                \
      gload16(aT_ + off_, smem + (BS) * 32768 + off_);                         \
      gload16(bT_ + off_, smem + 65536 + (BS) * 32768 + off_);                 \
    }                                                                          \
  } while (0)

#define PHASE(KS, FH, DO_STAGE, DO_VM) do {                                    \
    bf16x8 af[4];                                                              \
    const char* aB_ = smem + bufc * 32768 + ((KS) * 4 + hi) * 4096;            \
    _Pragma("unroll")                                                          \
    for (int f = 0; f < 4; ++f)                                                \
      af[f] = *(const bf16x8*)(aB_ + arow_b + ((FH) * 4 + f) * 256);           \
    if ((FH) == 0) {                                                           \
      const char* bB_ = smem + 65536 + bufc * 32768 + ((KS) * 4 + hi) * 4096;  \
      _Pragma("unroll")                                                        \
      for (int f = 0; f < 4; ++f)                                              \
        bfr[f] = *(const bf16x8*)(bB_ + brow_b + f * 256);                     \
    }                                                                          \
    DO_STAGE;                                                                  \
    DO_VM;                                                                     \
    __builtin_amdgcn_s_barrier();                                              \
    asm volatile("s_waitcnt lgkmcnt(0)" ::: "memory");                         \
    __builtin_amdgcn_s_setprio(1);                                             \
    _Pragma("unroll")                                                          \
    for (int fm = 0; fm < 4; ++fm)                                             \
      _Pragma("unroll")                                                        \
      for (int fn = 0; fn < 4; ++fn)                                           \
        acc[(FH) * 4 + fm][fn] = __builtin_amdgcn_mfma_f32_16x16x32_bf16(      \
            af[fm], bfr[fn], acc[(FH) * 4 + fm][fn], 0, 0, 0);                 \
    __builtin_amdgcn_s_setprio(0);                                             \
    __builtin_amdgcn_s_barrier();                                              \
  } while (0)

#define GEMM_PROLOGUE()                                                        \
  STAGE_FULL(0, 0);                                                            \
  asm volatile("s_waitcnt vmcnt(4)" ::: "memory");                             \
  __builtin_amdgcn_s_barrier();

#define GEMM_MAIN(NKT)                                                         \
  int bufc = 0;                                                                \
  for (int kt = 0; kt < (NKT); ++kt) {                                         \
    int ktn = (kt + 1 < (NKT)) ? kt + 1 : (NKT) - 1;  /* clamp: uniform counts */\
    int bn_ = bufc ^ 1;                                                        \
    PHASE(0, 0, STAGE_FULL(ktn, bn_), (void)0);                                \
    PHASE(0, 1, (void)0,                                                       \
          asm volatile("s_waitcnt vmcnt(8)" ::: "memory"));                    \
    PHASE(1, 0, (void)0, (void)0);                                             \
    PHASE(1, 1, (void)0,                                                       \
          asm volatile("s_waitcnt vmcnt(4)" ::: "memory"));                    \
    bufc ^= 1;                                                                 \
  }

// XCD-locality decode: all NTN blocks of one rt land on the same XCD
// (XCD ~ blockIdx % 8). bid = (rt/8)*(8*NTN) + nt*8 + (rt%8). Bijective since
// RT_MAX % 8 == 0.
__device__ __forceinline__ void rt_nt_decode(int bid, int NTN, int& rt, int& nt) {
  int grp = bid / (8 * NTN);
  int rem = bid - grp * 8 * NTN;
  rt = grp * 8 + (rem & 7);
  nt = rem >> 3;
}

// ---------------- GEMM1: h = relu2(A_tiled @ up_tiled^T), Hb written TILED ----------------
__global__ __launch_bounds__(NTHR, 2) void gemm_up8(
    const unsigned short* __restrict__ Ab, const unsigned short* __restrict__ Wt,
    unsigned short* __restrict__ Hb, const int* __restrict__ meta) {
  extern __shared__ char smem[];
  const int* pstart = meta + 16;
  int rt, nt;
  rt_nt_decode(blockIdx.x, NTN_UP, rt, nt);
  int row0 = rt * BM2;
  if (row0 >= pstart[NE]) return;
  int e = 0;
  #pragma unroll
  for (int q = 1; q < NE; ++q) if (row0 >= pstart[q]) e = q;

  int tid = threadIdx.x;
  int wv = tid >> 6, lane = tid & 63;
  int lane16 = lane * 16;

  const char* aTile = (const char*)Ab + (size_t)rt * NKT_UP * TILE_B;
  const char* bTile = (const char*)Wt + (size_t)(e * NTN_UP + nt) * NKT_UP * TILE_B;

  int wm = wv >> 2, wn = wv & 3;
  int hi = lane >> 4;
  int arow_b = (wm * 128 + (lane & 15)) * 16;   // byte offset of frag row base
  int brow_b = (wn * 64 + (lane & 15)) * 16;

  f32x4 acc[8][4] = {};
  bf16x8 bfr[4];

  GEMM_PROLOGUE();
  GEMM_MAIN(NKT_UP);                    // 32 K-tiles

  // epilogue: relu2 -> bf16 -> Hb tiled [rt][kt_dn][c][r][8]
  unsigned short* baseT = Hb + ((size_t)rt * NKT_DN + nt * 4 + wn) * TILE_S
                             + ((lane & 15) >> 3) * 2048 + (lane & 7);
  #pragma unroll
  for (int fm = 0; fm < 8; ++fm) {
    #pragma unroll
    for (int j = 0; j < 4; ++j) {
      int r = wm * 128 + hi * 4 + fm * 16 + j;
      unsigned short* rb = baseT + r * 8;
      #pragma unroll
      for (int fn = 0; fn < 4; ++fn) {
        float v = acc[fm][fn][j];
        v = v > 0.f ? v * v : 0.f;
        rb[fn * 4096] = f2bf(v);        // fn*2 chunks * 2048 shorts
      }
    }
  }
}

// ---------------- GEMM2: ybuf[pair] = h @ down_tiled^T ----------------
__global__ __launch_bounds__(NTHR, 2) void gemm_down8(
    const unsigned short* __restrict__ Hb, const unsigned short* __restrict__ Wt,
    unsigned short* __restrict__ Yb, const int* __restrict__ meta,
    const int* __restrict__ tok) {
  extern __shared__ char smem[];
  const int* pstart = meta + 16;
  int rt, nt;
  rt_nt_decode(blockIdx.x, NTN_DN, rt, nt);
  int row0 = rt * BM2;
  if (row0 >= pstart[NE]) return;
  int e = 0;
  #pragma unroll
  for (int q = 1; q < NE; ++q) if (row0 >= pstart[q]) e = q;

  int tid = threadIdx.x;
  int wv = tid >> 6, lane = tid & 63;
  int lane16 = lane * 16;

  const char* aTile = (const char*)Hb + (size_t)rt * NKT_DN * TILE_B;
  const char* bTile = (const char*)Wt + (size_t)(e * NTN_DN + nt) * NKT_DN * TILE_B;

  int wm = wv >> 2, wn = wv & 3;
  int hi = lane >> 4;
  int arow_b = (wm * 128 + (lane & 15)) * 16;
  int brow_b = (wn * 64 + (lane & 15)) * 16;

  f32x4 acc[8][4] = {};
  bf16x8 bfr[4];

  GEMM_PROLOGUE();
  GEMM_MAIN(NKT_DN);                    // 64 K-tiles

  int crow0 = row0 + wm * 128 + hi * 4;
  int ccol0 = nt * BN2 + wn * 64 + (lane & 15);
  #pragma unroll
  for (int fm = 0; fm < 8; ++fm) {
    #pragma unroll
    for (int j = 0; j < 4; ++j) {
      int p = crow0 + fm * 16 + j;
      int i = tok[p];
      if (i < 0) continue;              // padding row
      unsigned short* dst = Yb + (size_t)i * H_DIM + ccol0;
      #pragma unroll
      for (int fn = 0; fn < 4; ++fn)
        dst[fn * 16] = f2bf(acc[fm][fn][j]);
    }
  }
}

// ---------------- combine: out[t] = w0*y[2t] + w1*y[2t+1] (4 tokens/block) ----------------
__global__ __launch_bounds__(256) void combine(
    const unsigned short* __restrict__ Yb, const float* __restrict__ tkw,
    float* __restrict__ out) {
  int h0 = threadIdx.x * 8;
  #pragma unroll
  for (int tt = 0; tt < 4; ++tt) {
    int t = blockIdx.x * 4 + tt;
    float w0 = tkw[2 * t], w1 = tkw[2 * t + 1];
    bf16x8 ya = *(const bf16x8*)(Yb + (size_t)(2 * t) * H_DIM + h0);
    bf16x8 yb = *(const bf16x8*)(Yb + (size_t)(2 * t + 1) * H_DIM + h0);
    float* dst = out + (size_t)t * H_DIM + h0;
    float4 o0, o1;
    o0.x = w0 * b2f((unsigned short)ya[0]) + w1 * b2f((unsigned short)yb[0]);
    o0.y = w0 * b2f((unsigned short)ya[1]) + w1 * b2f((unsigned short)yb[1]);
    o0.z = w0 * b2f((unsigned short)ya[2]) + w1 * b2f((unsigned short)yb[2]);
    o0.w = w0 * b2f((unsigned short)ya[3]) + w1 * b2f((unsigned short)yb[3]);
    o1.x = w0 * b2f((unsigned short)ya[4]) + w1 * b2f((unsigned short)yb[4]);
    o1.y = w0 * b2f((unsigned short)ya[5]) + w1 * b2f((unsigned short)yb[5]);
    o1.z = w0 * b2f((unsigned short)ya[6]) + w1 * b2f((unsigned short)yb[6]);
    o1.w = w0 * b2f((unsigned short)ya[7]) + w1 * b2f((unsigned short)yb[7]);
    ((float4*)dst)[0] = o0;
    ((float4*)dst)[1] = o1;
  }
}

// ---------------- launch ----------------
extern "C" void kernel_launch(void* const* d_in, const int* in_sizes, int n_in,
                              void* d_out, int out_size, void* d_ws, size_t ws_size,
                              hipStream_t stream) {
  const float* x   = (const float*)d_in[0];
  const int*   tki = (const int*)d_in[1];
  const float* tkw = (const float*)d_in[2];
  const float* up  = (const float*)d_in[3];
  const float* dn  = (const float*)d_in[4];
  float* out = (float*)d_out;
  char* ws = (char*)d_ws;

  unsigned short* ab  = (unsigned short*)(ws + WS_AB);   // tiled A (up)
  unsigned short* wt  = (unsigned short*)(ws + WS_W);    // tiled weights (up->down)
  unsigned short* hb  = (unsigned short*)(ws + WS_H);    // tiled H
  int*            tok = (int*)(ws + WS_TOK);
  unsigned short* yb  = (unsigned short*)(ws + WS_AB);   // Yb overlaps dead Ab
  int*            meta= (int*)(ws + WS_META);

  hipFuncSetAttribute((const void*)gemm_up8,
                      hipFuncAttributeMaxDynamicSharedMemorySize, 131072);
  hipFuncSetAttribute((const void*)gemm_down8,
                      hipFuncAttributeMaxDynamicSharedMemorySize, 131072);

  route_all<<<1, 512, 0, stream>>>(tki, meta, tok);

  gather_tile_x<<<RT_MAX * 8, 512, 0, stream>>>(x, tok, ab);
  cvt_tile_w<<<NE * NTN_UP * 32, 512, 0, stream>>>(up, wt, NKT_UP, 11);

  gemm_up8<<<RT_MAX * NTN_UP, NTHR, 131072, stream>>>(ab, wt, hb, meta);

  cvt_tile_w<<<NE * NTN_DN * 32, 512, 0, stream>>>(dn, wt, NKT_DN, 12);

  gemm_down8<<<RT_MAX * NTN_DN, NTHR, 131072, stream>>>(hb, wt, yb, meta, tok);

  combine<<<T_TOKENS / 4, 256, 0, stream>>>(yb, tkw, out);
}

// Round 8
// 1018.720 us; speedup vs baseline: 1.1678x; 1.1678x over previous
//
#include <hip/hip_runtime.h>

// ---------------- problem constants ----------------
#define T_TOKENS 8192
#define H_DIM    2048
#define I_DIM    4096
#define NE       8
#define NPAIR    16384                  // T_TOKENS * TOP_K
#define PADBM    256                    // expert segment padding (= BM of GEMM tiles)
#define PADP     (NPAIR + NE * PADBM)   // 18432 worst-case padded rows
#define RT_MAX   (PADP / PADBM)         // 72 max row tiles (72 = 9*8, XCD-exact)

// 256x256x64 8-phase GEMM geometry
#define BM2 256
#define BN2 256
#define BK2 64
#define NTHR 512
#define NKT_UP (H_DIM / BK2)            // 32
#define NKT_DN (I_DIM / BK2)            // 64
#define NTN_UP (I_DIM / BN2)            // 16
#define NTN_DN (H_DIM / BN2)            // 8
#define TILE_B 32768                    // bytes per 256x64 bf16 operand tile
#define TILE_S 16384                    // shorts per tile

// ---------------- workspace layout (bytes) ----------------
#define WS_AB   0ull
#define WS_W    (WS_AB + (size_t)RT_MAX * NKT_UP * TILE_B)
#define WS_H    (WS_W + (size_t)NE * I_DIM * H_DIM * 2)
#define WS_TOK  (WS_H + (size_t)RT_MAX * NKT_DN * TILE_B)
#define WS_META (WS_TOK + (size_t)PADP * 4)

typedef __attribute__((ext_vector_type(8))) short bf16x8;   // 8 bf16 = 4 VGPRs
typedef __attribute__((ext_vector_type(4))) float f32x4;    // MFMA C/D

__device__ __forceinline__ unsigned short f2bf(float f) {
  union { float f; unsigned u; } a; a.f = f;
  unsigned r = a.u + 0x7fffu + ((a.u >> 16) & 1u);   // RNE
  return (unsigned short)(r >> 16);
}

__device__ __forceinline__ float b2f(unsigned short b) {
  union { unsigned u; float f; } a; a.u = ((unsigned)b) << 16;
  return a.f;
}

__device__ __forceinline__ bf16x8 pack8(float4 a, float4 b) {
  bf16x8 o;
  o[0] = (short)f2bf(a.x); o[1] = (short)f2bf(a.y);
  o[2] = (short)f2bf(a.z); o[3] = (short)f2bf(a.w);
  o[4] = (short)f2bf(b.x); o[5] = (short)f2bf(b.y);
  o[6] = (short)f2bf(b.z); o[7] = (short)f2bf(b.w);
  return o;
}

__device__ __forceinline__ void gload16(const void* g, void* l) {
  __builtin_amdgcn_global_load_lds(
      (const __attribute__((address_space(1))) unsigned int*)g,
      (__attribute__((address_space(3))) unsigned int*)l,
      16, 0, 0);
}

// LDS bank-spread involution for [c][r][16B] tiles: XOR bits 5:6 with bits 7:8.
// Applied identically on write and read (self-inverse).
__device__ __forceinline__ int swz(int a) { return a ^ ((a >> 2) & 0x60); }

// ---------------- routing: single-block count/scan/scatter + tok init ----------------
__global__ __launch_bounds__(512) void route_all(const int* __restrict__ idx,
                                                 int* __restrict__ meta,
                                                 int* __restrict__ tok) {
  __shared__ int cnt[NE], base[NE + 1], cur[NE];
  int t = threadIdx.x;
  if (t < NE) { cnt[t] = 0; cur[t] = 0; }
  for (int i = t; i < PADP; i += 512) tok[i] = -1;   // -1 = padding
  __syncthreads();
  for (int i = t; i < NPAIR; i += 512) atomicAdd(&cnt[idx[i]], 1);
  __syncthreads();
  if (t == 0) {
    int off = 0;
    for (int e = 0; e < NE; ++e) {
      base[e] = off;
      off += ((cnt[e] + PADBM - 1) / PADBM) * PADBM;
    }
    base[NE] = off;
    for (int e = 0; e <= NE; ++e) meta[16 + e] = base[e];
  }
  __syncthreads();
  for (int i = t; i < NPAIR; i += 512) {
    int e = idx[i];
    int pos = base[e] + atomicAdd(&cur[e], 1);
    tok[pos] = i;                       // pair index; token = i>>1 (TOP_K=2)
  }
}

// ---------------- weight fp32 -> tiled bf16 (LDS-staged transpose) ----------------
// Block = one 256x64 output tile (panel, kt). Reads: 2 thr/row x 128B contiguous.
// LDS tiled write (swizzled, conflict-free). Linear 32KB global write.
__global__ __launch_bounds__(512) void cvt_tile_w(
    const float* __restrict__ W, unsigned short* __restrict__ out,
    int NKT, int K) {
  __shared__ float4 ltq[TILE_B / 16];
  char* lt = (char*)ltq;
  int kt = blockIdx.x % NKT, panel = blockIdx.x / NKT;
  int t = threadIdx.x, r = t >> 1, half = t & 1;
  const float* src = W + ((size_t)panel * 256 + r) * K + kt * 64 + half * 32;
  float4 v[8];
  #pragma unroll
  for (int i = 0; i < 8; ++i) v[i] = ((const float4*)src)[i];
  #pragma unroll
  for (int i2 = 0; i2 < 4; ++i2) {
    int c = half * 4 + i2;
    *(bf16x8*)(lt + swz(c * 4096 + r * 16)) = pack8(v[2 * i2], v[2 * i2 + 1]);
  }
  __syncthreads();
  char* dst = (char*)(out + (size_t)blockIdx.x * TILE_S);
  int tb = t * 16;
  #pragma unroll
  for (int i = 0; i < 4; ++i) {
    int o = i * 8192 + tb;
    *(bf16x8*)(dst + o) = *(const bf16x8*)(lt + swz(o));
  }
}

// ---------------- gathered x fp32 -> tiled bf16 A (LDS-staged) ----------------
__global__ __launch_bounds__(512) void gather_tile_x(
    const float* __restrict__ x, const int* __restrict__ tok,
    unsigned short* __restrict__ out) {
  __shared__ float4 ltq[TILE_B / 16];
  char* lt = (char*)ltq;
  int kt = blockIdx.x & (NKT_UP - 1), rt = blockIdx.x >> 5;
  int t = threadIdx.x, r = t >> 1, half = t & 1;
  int v = tok[rt * 256 + r];
  bf16x8 pk[4];
  if (v < 0) {
    #pragma unroll
    for (int i2 = 0; i2 < 4; ++i2) pk[i2] = (bf16x8)0;
  } else {
    const float* src = x + (size_t)(v >> 1) * H_DIM + kt * 64 + half * 32;
    float4 w[8];
    #pragma unroll
    for (int i = 0; i < 8; ++i) w[i] = ((const float4*)src)[i];
    #pragma unroll
    for (int i2 = 0; i2 < 4; ++i2) pk[i2] = pack8(w[2 * i2], w[2 * i2 + 1]);
  }
  #pragma unroll
  for (int i2 = 0; i2 < 4; ++i2) {
    int c = half * 4 + i2;
    *(bf16x8*)(lt + swz(c * 4096 + r * 16)) = pk[i2];
  }
  __syncthreads();
  char* dst = (char*)(out + (size_t)blockIdx.x * TILE_S);   // [rt][kt] order
  int tb = t * 16;
  #pragma unroll
  for (int i = 0; i < 4; ++i) {
    int o = i * 8192 + tb;
    *(bf16x8*)(dst + o) = *(const bf16x8*)(lt + swz(o));
  }
}

// ---------------- 8-phase 256^2 grouped-GEMM core (linear tiled staging) ----------------
// LDS: A dbuf [2][32KB] at 0; B dbuf at 65536. Stage = linear 32KB copy per operand.
// vmcnt(8)@c1 (tile t fully landed), vmcnt(4)@c3 (ks=0 of t+1 landed).
// Never drains to 0 in main loop.

#define STAGE_FULL(KT, BS) do {                                                \
    const char* aT_ = aTile + (size_t)(KT) * TILE_B;                           \
    const char* bT_ = bTile + (size_t)(KT) * TILE_B;                           \
    _Pragma("unroll")                                                          \
    for (int l_ = 0; l_ < 4; ++l_) {                                           \
      int off_ = (l_ * 8 + wv) * 1024 + lane16;                                \
      gload16(aT_ + off_, smem + (BS) * 32768 + off_);                         \
      gload16(bT_ + off_, smem + 65536 + (BS) * 32768 + off_);                 \
    }                                                                          \
  } while (0)

#define PHASE(KS, FH, DO_STAGE, DO_VM) do {                                    \
    bf16x8 af[4];                                                              \
    const char* aB_ = smem + bufc * 32768 + ((KS) * 4 + hi) * 4096;            \
    _Pragma("unroll")                                                          \
    for (int f = 0; f < 4; ++f)                                                \
      af[f] = *(const bf16x8*)(aB_ + arow_b + ((FH) * 4 + f) * 256);           \
    if ((FH) == 0) {                                                           \
      const char* bB_ = smem + 65536 + bufc * 32768 + ((KS) * 4 + hi) * 4096;  \
      _Pragma("unroll")                                                        \
      for (int f = 0; f < 4; ++f)                                              \
        bfr[f] = *(const bf16x8*)(bB_ + brow_b + f * 256);                     \
    }                                                                          \
    DO_STAGE;                                                                  \
    DO_VM;                                                                     \
    __builtin_amdgcn_s_barrier();                                              \
    asm volatile("s_waitcnt lgkmcnt(0)" ::: "memory");                         \
    __builtin_amdgcn_s_setprio(1);                                             \
    _Pragma("unroll")                                                          \
    for (int fm = 0; fm < 4; ++fm)                                             \
      _Pragma("unroll")                                                        \
      for (int fn = 0; fn < 4; ++fn)                                           \
        acc[(FH) * 4 + fm][fn] = __builtin_amdgcn_mfma_f32_16x16x32_bf16(      \
            af[fm], bfr[fn], acc[(FH) * 4 + fm][fn], 0, 0, 0);                 \
    __builtin_amdgcn_s_setprio(0);                                             \
    __builtin_amdgcn_s_barrier();                                              \
  } while (0)

#define GEMM_PROLOGUE()                                                        \
  STAGE_FULL(0, 0);                                                            \
  asm volatile("s_waitcnt vmcnt(4)" ::: "memory");                             \
  __builtin_amdgcn_s_barrier();

#define GEMM_MAIN(NKT)                                                         \
  int bufc = 0;                                                                \
  for (int kt = 0; kt < (NKT); ++kt) {                                         \
    int ktn = (kt + 1 < (NKT)) ? kt + 1 : (NKT) - 1;  /* clamp: uniform counts */\
    int bn_ = bufc ^ 1;                                                        \
    PHASE(0, 0, STAGE_FULL(ktn, bn_), (void)0);                                \
    PHASE(0, 1, (void)0,                                                       \
          asm volatile("s_waitcnt vmcnt(8)" ::: "memory"));                    \
    PHASE(1, 0, (void)0, (void)0);                                             \
    PHASE(1, 1, (void)0,                                                       \
          asm volatile("s_waitcnt vmcnt(4)" ::: "memory"));                    \
    bufc ^= 1;                                                                 \
  }

// XCD-locality decode: all NTN blocks of one rt land on the same XCD.
__device__ __forceinline__ void rt_nt_decode(int bid, int NTN, int& rt, int& nt) {
  int grp = bid / (8 * NTN);
  int rem = bid - grp * 8 * NTN;
  rt = grp * 8 + (rem & 7);
  nt = rem >> 3;
}

// ---------------- GEMM1: h = relu2(A_tiled @ up_tiled^T), Hb written TILED ----------------
__global__ __launch_bounds__(NTHR, 2) void gemm_up8(
    const unsigned short* __restrict__ Ab, const unsigned short* __restrict__ Wt,
    unsigned short* __restrict__ Hb, const int* __restrict__ meta) {
  extern __shared__ char smem[];
  const int* pstart = meta + 16;
  int rt, nt;
  rt_nt_decode(blockIdx.x, NTN_UP, rt, nt);
  int row0 = rt * BM2;
  if (row0 >= pstart[NE]) return;
  int e = 0;
  #pragma unroll
  for (int q = 1; q < NE; ++q) if (row0 >= pstart[q]) e = q;

  int tid = threadIdx.x;
  int wv = tid >> 6, lane = tid & 63;
  int lane16 = lane * 16;

  const char* aTile = (const char*)Ab + (size_t)rt * NKT_UP * TILE_B;
  const char* bTile = (const char*)Wt + (size_t)(e * NTN_UP + nt) * NKT_UP * TILE_B;

  int wm = wv >> 2, wn = wv & 3;
  int hi = lane >> 4;
  int arow_b = (wm * 128 + (lane & 15)) * 16;   // byte offset of frag row base
  int brow_b = (wn * 64 + (lane & 15)) * 16;

  f32x4 acc[8][4] = {};
  bf16x8 bfr[4];

  GEMM_PROLOGUE();
  GEMM_MAIN(NKT_UP);                    // 32 K-tiles

  // epilogue: relu2 -> bf16 -> Hb tiled [rt][kt_dn][c][r][8]
  unsigned short* baseT = Hb + ((size_t)rt * NKT_DN + nt * 4 + wn) * TILE_S
                             + ((lane & 15) >> 3) * 2048 + (lane & 7);
  #pragma unroll
  for (int fm = 0; fm < 8; ++fm) {
    #pragma unroll
    for (int j = 0; j < 4; ++j) {
      int r = wm * 128 + hi * 4 + fm * 16 + j;
      unsigned short* rb = baseT + r * 8;
      #pragma unroll
      for (int fn = 0; fn < 4; ++fn) {
        float v = acc[fm][fn][j];
        v = v > 0.f ? v * v : 0.f;
        rb[fn * 4096] = f2bf(v);        // fn*2 chunks * 2048 shorts
      }
    }
  }
}

// ---------------- GEMM2: ybuf[pair] = h @ down_tiled^T ----------------
__global__ __launch_bounds__(NTHR, 2) void gemm_down8(
    const unsigned short* __restrict__ Hb, const unsigned short* __restrict__ Wt,
    unsigned short* __restrict__ Yb, const int* __restrict__ meta,
    const int* __restrict__ tok) {
  extern __shared__ char smem[];
  const int* pstart = meta + 16;
  int rt, nt;
  rt_nt_decode(blockIdx.x, NTN_DN, rt, nt);
  int row0 = rt * BM2;
  if (row0 >= pstart[NE]) return;
  int e = 0;
  #pragma unroll
  for (int q = 1; q < NE; ++q) if (row0 >= pstart[q]) e = q;

  int tid = threadIdx.x;
  int wv = tid >> 6, lane = tid & 63;
  int lane16 = lane * 16;

  const char* aTile = (const char*)Hb + (size_t)rt * NKT_DN * TILE_B;
  const char* bTile = (const char*)Wt + (size_t)(e * NTN_DN + nt) * NKT_DN * TILE_B;

  int wm = wv >> 2, wn = wv & 3;
  int hi = lane >> 4;
  int arow_b = (wm * 128 + (lane & 15)) * 16;
  int brow_b = (wn * 64 + (lane & 15)) * 16;

  f32x4 acc[8][4] = {};
  bf16x8 bfr[4];

  GEMM_PROLOGUE();
  GEMM_MAIN(NKT_DN);                    // 64 K-tiles

  int crow0 = row0 + wm * 128 + hi * 4;
  int ccol0 = nt * BN2 + wn * 64 + (lane & 15);
  #pragma unroll
  for (int fm = 0; fm < 8; ++fm) {
    #pragma unroll
    for (int j = 0; j < 4; ++j) {
      int p = crow0 + fm * 16 + j;
      int i = tok[p];
      if (i < 0) continue;              // padding row
      unsigned short* dst = Yb + (size_t)i * H_DIM + ccol0;
      #pragma unroll
      for (int fn = 0; fn < 4; ++fn)
        dst[fn * 16] = f2bf(acc[fm][fn][j]);
    }
  }
}

// ---------------- combine: out[t] = w0*y[2t] + w1*y[2t+1] (4 tokens/block) ----------------
__global__ __launch_bounds__(256) void combine(
    const unsigned short* __restrict__ Yb, const float* __restrict__ tkw,
    float* __restrict__ out) {
  int h0 = threadIdx.x * 8;
  #pragma unroll
  for (int tt = 0; tt < 4; ++tt) {
    int t = blockIdx.x * 4 + tt;
    float w0 = tkw[2 * t], w1 = tkw[2 * t + 1];
    bf16x8 ya = *(const bf16x8*)(Yb + (size_t)(2 * t) * H_DIM + h0);
    bf16x8 yb = *(const bf16x8*)(Yb + (size_t)(2 * t + 1) * H_DIM + h0);
    float* dst = out + (size_t)t * H_DIM + h0;
    float4 o0, o1;
    o0.x = w0 * b2f((unsigned short)ya[0]) + w1 * b2f((unsigned short)yb[0]);
    o0.y = w0 * b2f((unsigned short)ya[1]) + w1 * b2f((unsigned short)yb[1]);
    o0.z = w0 * b2f((unsigned short)ya[2]) + w1 * b2f((unsigned short)yb[2]);
    o0.w = w0 * b2f((unsigned short)ya[3]) + w1 * b2f((unsigned short)yb[3]);
    o1.x = w0 * b2f((unsigned short)ya[4]) + w1 * b2f((unsigned short)yb[4]);
    o1.y = w0 * b2f((unsigned short)ya[5]) + w1 * b2f((unsigned short)yb[5]);
    o1.z = w0 * b2f((unsigned short)ya[6]) + w1 * b2f((unsigned short)yb[6]);
    o1.w = w0 * b2f((unsigned short)ya[7]) + w1 * b2f((unsigned short)yb[7]);
    ((float4*)dst)[0] = o0;
    ((float4*)dst)[1] = o1;
  }
}

// ---------------- launch ----------------
extern "C" void kernel_launch(void* const* d_in, const int* in_sizes, int n_in,
                              void* d_out, int out_size, void* d_ws, size_t ws_size,
                              hipStream_t stream) {
  const float* x   = (const float*)d_in[0];
  const int*   tki = (const int*)d_in[1];
  const float* tkw = (const float*)d_in[2];
  const float* up  = (const float*)d_in[3];
  const float* dn  = (const float*)d_in[4];
  float* out = (float*)d_out;
  char* ws = (char*)d_ws;

  unsigned short* ab  = (unsigned short*)(ws + WS_AB);   // tiled A (up)
  unsigned short* wt  = (unsigned short*)(ws + WS_W);    // tiled weights (up->down)
  unsigned short* hb  = (unsigned short*)(ws + WS_H);    // tiled H
  int*            tok = (int*)(ws + WS_TOK);
  unsigned short* yb  = (unsigned short*)(ws + WS_AB);   // Yb overlaps dead Ab
  int*            meta= (int*)(ws + WS_META);

  hipFuncSetAttribute((const void*)gemm_up8,
                      hipFuncAttributeMaxDynamicSharedMemorySize, 131072);
  hipFuncSetAttribute((const void*)gemm_down8,
                      hipFuncAttributeMaxDynamicSharedMemorySize, 131072);

  route_all<<<1, 512, 0, stream>>>(tki, meta, tok);

  gather_tile_x<<<RT_MAX * NKT_UP, 512, 0, stream>>>(x, tok, ab);
  cvt_tile_w<<<NE * NTN_UP * NKT_UP, 512, 0, stream>>>(up, wt, NKT_UP, H_DIM);

  gemm_up8<<<RT_MAX * NTN_UP, NTHR, 131072, stream>>>(ab, wt, hb, meta);

  cvt_tile_w<<<NE * NTN_DN * NKT_DN, 512, 0, stream>>>(dn, wt, NKT_DN, I_DIM);

  gemm_down8<<<RT_MAX * NTN_DN, NTHR, 131072, stream>>>(hb, wt, yb, meta, tok);

  combine<<<T_TOKENS / 4, 256, 0, stream>>>(yb, tkw, out);
}

// Round 9
// 1008.581 us; speedup vs baseline: 1.1796x; 1.0101x over previous
//
#include <hip/hip_runtime.h>

// ---------------- problem constants ----------------
#define T_TOKENS 8192
#define H_DIM    2048
#define I_DIM    4096
#define NE       8
#define NPAIR    16384                  // T_TOKENS * TOP_K
#define PADBM    256                    // expert segment padding (= BM of GEMM tiles)
#define PADP     (NPAIR + NE * PADBM)   // 18432 worst-case padded rows
#define RT_MAX   (PADP / PADBM)         // 72 max row tiles (72 = 9*8, XCD-exact)

// 256x256x64 8-phase GEMM geometry
#define BM2 256
#define BN2 256
#define BK2 64
#define NTHR 512
#define NKT_UP (H_DIM / BK2)            // 32
#define NKT_DN (I_DIM / BK2)            // 64
#define NTN_UP (I_DIM / BN2)            // 16
#define NTN_DN (H_DIM / BN2)            // 8
#define TILE_B 32768                    // bytes per 256x64 bf16 operand tile
#define TILE_S 16384                    // shorts per tile

// ---------------- workspace layout (bytes) ----------------
#define WS_AB   0ull
#define WS_W    (WS_AB + (size_t)RT_MAX * NKT_UP * TILE_B)
#define WS_H    (WS_W + (size_t)NE * I_DIM * H_DIM * 2)
#define WS_TOK  (WS_H + (size_t)RT_MAX * NKT_DN * TILE_B)
#define WS_META (WS_TOK + (size_t)PADP * 4)

typedef __attribute__((ext_vector_type(8))) short bf16x8;   // 8 bf16 = 4 VGPRs
typedef __attribute__((ext_vector_type(4))) float f32x4;    // MFMA C/D

__device__ __forceinline__ unsigned short f2bf(float f) {
  union { float f; unsigned u; } a; a.f = f;
  unsigned r = a.u + 0x7fffu + ((a.u >> 16) & 1u);   // RNE
  return (unsigned short)(r >> 16);
}

__device__ __forceinline__ float b2f(unsigned short b) {
  union { unsigned u; float f; } a; a.u = ((unsigned)b) << 16;
  return a.f;
}

__device__ __forceinline__ bf16x8 pack8(float4 a, float4 b) {
  bf16x8 o;
  o[0] = (short)f2bf(a.x); o[1] = (short)f2bf(a.y);
  o[2] = (short)f2bf(a.z); o[3] = (short)f2bf(a.w);
  o[4] = (short)f2bf(b.x); o[5] = (short)f2bf(b.y);
  o[6] = (short)f2bf(b.z); o[7] = (short)f2bf(b.w);
  return o;
}

__device__ __forceinline__ void gload16(const void* g, void* l) {
  __builtin_amdgcn_global_load_lds(
      (const __attribute__((address_space(1))) unsigned int*)g,
      (__attribute__((address_space(3))) unsigned int*)l,
      16, 0, 0);
}

// LDS bank-spread involution for [c][r][16B] tiles: XOR bits 5:6 with bits 7:8.
__device__ __forceinline__ int swz(int a) { return a ^ ((a >> 2) & 0x60); }

// ---------------- routing: single-block count/scan/scatter + tok init ----------------
__global__ __launch_bounds__(512) void route_all(const int* __restrict__ idx,
                                                 int* __restrict__ meta,
                                                 int* __restrict__ tok) {
  __shared__ int cnt[NE], base[NE + 1], cur[NE];
  int t = threadIdx.x;
  if (t < NE) { cnt[t] = 0; cur[t] = 0; }
  for (int i = t; i < PADP; i += 512) tok[i] = -1;   // -1 = padding
  __syncthreads();
  for (int i = t; i < NPAIR; i += 512) atomicAdd(&cnt[idx[i]], 1);
  __syncthreads();
  if (t == 0) {
    int off = 0;
    for (int e = 0; e < NE; ++e) {
      base[e] = off;
      off += ((cnt[e] + PADBM - 1) / PADBM) * PADBM;
    }
    base[NE] = off;
    for (int e = 0; e <= NE; ++e) meta[16 + e] = base[e];
  }
  __syncthreads();
  for (int i = t; i < NPAIR; i += 512) {
    int e = idx[i];
    int pos = base[e] + atomicAdd(&cur[e], 1);
    tok[pos] = i;                       // pair index; token = i>>1 (TOP_K=2)
  }
}

// ---------------- weight fp32 -> tiled bf16 (LDS-staged transpose) ----------------
__global__ __launch_bounds__(512) void cvt_tile_w(
    const float* __restrict__ W, unsigned short* __restrict__ out,
    int NKT, int K) {
  __shared__ float4 ltq[TILE_B / 16];
  char* lt = (char*)ltq;
  int kt = blockIdx.x % NKT, panel = blockIdx.x / NKT;
  int t = threadIdx.x, r = t >> 1, half = t & 1;
  const float* src = W + ((size_t)panel * 256 + r) * K + kt * 64 + half * 32;
  float4 v[8];
  #pragma unroll
  for (int i = 0; i < 8; ++i) v[i] = ((const float4*)src)[i];
  #pragma unroll
  for (int i2 = 0; i2 < 4; ++i2) {
    int c = half * 4 + i2;
    *(bf16x8*)(lt + swz(c * 4096 + r * 16)) = pack8(v[2 * i2], v[2 * i2 + 1]);
  }
  __syncthreads();
  char* dst = (char*)(out + (size_t)blockIdx.x * TILE_S);
  int tb = t * 16;
  #pragma unroll
  for (int i = 0; i < 4; ++i) {
    int o = i * 8192 + tb;
    *(bf16x8*)(dst + o) = *(const bf16x8*)(lt + swz(o));
  }
}

// ---------------- gathered x fp32 -> tiled bf16 A (LDS-staged) ----------------
__global__ __launch_bounds__(512) void gather_tile_x(
    const float* __restrict__ x, const int* __restrict__ tok,
    unsigned short* __restrict__ out) {
  __shared__ float4 ltq[TILE_B / 16];
  char* lt = (char*)ltq;
  int kt = blockIdx.x & (NKT_UP - 1), rt = blockIdx.x >> 5;
  int t = threadIdx.x, r = t >> 1, half = t & 1;
  int v = tok[rt * 256 + r];
  bf16x8 pk[4];
  if (v < 0) {
    #pragma unroll
    for (int i2 = 0; i2 < 4; ++i2) pk[i2] = (bf16x8)0;
  } else {
    const float* src = x + (size_t)(v >> 1) * H_DIM + kt * 64 + half * 32;
    float4 w[8];
    #pragma unroll
    for (int i = 0; i < 8; ++i) w[i] = ((const float4*)src)[i];
    #pragma unroll
    for (int i2 = 0; i2 < 4; ++i2) pk[i2] = pack8(w[2 * i2], w[2 * i2 + 1]);
  }
  #pragma unroll
  for (int i2 = 0; i2 < 4; ++i2) {
    int c = half * 4 + i2;
    *(bf16x8*)(lt + swz(c * 4096 + r * 16)) = pk[i2];
  }
  __syncthreads();
  char* dst = (char*)(out + (size_t)blockIdx.x * TILE_S);   // [rt][kt] order
  int tb = t * 16;
  #pragma unroll
  for (int i = 0; i < 4; ++i) {
    int o = i * 8192 + tb;
    *(bf16x8*)(dst + o) = *(const bf16x8*)(lt + swz(o));
  }
}

// ---------------- 8-phase 256^2 grouped-GEMM core (linear tiled staging) ----------------
// LDS: A dbuf [2][32KB] at 0; B dbuf at 65536. Stage = linear 32KB copy per operand.
// vmcnt(8)@c1 (tile t fully landed), vmcnt(4)@c3 (ks=0 of t+1 landed).

#define STAGE_FULL(KT, BS) do {                                                \
    const char* aT_ = aTile + (size_t)(KT) * TILE_B;                           \
    const char* bT_ = bTile + (size_t)(KT) * TILE_B;                           \
    _Pragma("unroll")                                                          \
    for (int l_ = 0; l_ < 4; ++l_) {                                           \
      int off_ = (l_ * 8 + wv) * 1024 + lane16;                                \
      gload16(aT_ + off_, smem + (BS) * 32768 + off_);                         \
      gload16(bT_ + off_, smem + 65536 + (BS) * 32768 + off_);                 \
    }                                                                          \
  } while (0)

#define PHASE(KS, FH, DO_STAGE, DO_VM) do {                                    \
    bf16x8 af[4];                                                              \
    const char* aB_ = smem + bufc * 32768 + ((KS) * 4 + hi) * 4096;            \
    _Pragma("unroll")                                                          \
    for (int f = 0; f < 4; ++f)                                                \
      af[f] = *(const bf16x8*)(aB_ + arow_b + ((FH) * 4 + f) * 256);           \
    if ((FH) == 0) {                                                           \
      const char* bB_ = smem + 65536 + bufc * 32768 + ((KS) * 4 + hi) * 4096;  \
      _Pragma("unroll")                                                        \
      for (int f = 0; f < 4; ++f)                                              \
        bfr[f] = *(const bf16x8*)(bB_ + brow_b + f * 256);                     \
    }                                                                          \
    DO_STAGE;                                                                  \
    DO_VM;                                                                     \
    __builtin_amdgcn_s_barrier();                                              \
    asm volatile("s_waitcnt lgkmcnt(0)" ::: "memory");                         \
    __builtin_amdgcn_s_setprio(1);                                             \
    _Pragma("unroll")                                                          \
    for (int fm = 0; fm < 4; ++fm)                                             \
      _Pragma("unroll")                                                        \
      for (int fn = 0; fn < 4; ++fn)                                           \
        acc[(FH) * 4 + fm][fn] = __builtin_amdgcn_mfma_f32_16x16x32_bf16(      \
            af[fm], bfr[fn], acc[(FH) * 4 + fm][fn], 0, 0, 0);                 \
    __builtin_amdgcn_s_setprio(0);                                             \
    __builtin_amdgcn_s_barrier();                                              \
  } while (0)

#define GEMM_PROLOGUE()                                                        \
  STAGE_FULL(0, 0);                                                            \
  asm volatile("s_waitcnt vmcnt(4)" ::: "memory");                             \
  __builtin_amdgcn_s_barrier();

#define GEMM_MAIN(NKT)                                                         \
  int bufc = 0;                                                                \
  for (int kt = 0; kt < (NKT); ++kt) {                                         \
    int ktn = (kt + 1 < (NKT)) ? kt + 1 : (NKT) - 1;  /* clamp: uniform counts */\
    int bn_ = bufc ^ 1;                                                        \
    PHASE(0, 0, STAGE_FULL(ktn, bn_), (void)0);                                \
    PHASE(0, 1, (void)0,                                                       \
          asm volatile("s_waitcnt vmcnt(8)" ::: "memory"));                    \
    PHASE(1, 0, (void)0, (void)0);                                             \
    PHASE(1, 1, (void)0,                                                       \
          asm volatile("s_waitcnt vmcnt(4)" ::: "memory"));                    \
    bufc ^= 1;                                                                 \
  }

// 2D XCD-locality decode: XCD(bid%8) = (rt%4)*2 + (nt%2).
// A panel's nt-sharers span 2 XCDs; B tile's rt-sharers span 4 XCDs
// (vs 1/8 before) -> L3 stage traffic ~ -36%, difference becomes L2 hits.
// Bijective: RT_MAX%4==0, NTN even.
__device__ __forceinline__ void rt_nt_decode(int bid, int NTN, int& rt, int& nt) {
  int xcd = bid & 7, g = bid >> 3;
  int gh = NTN >> 1;
  int gn = g % gh, gr = g / gh;
  rt = gr * 4 + (xcd >> 1);
  nt = gn * 2 + (xcd & 1);
}

// ---------------- GEMM1: h = relu2(A_tiled @ up_tiled^T), Hb written TILED ----------------
__global__ __launch_bounds__(NTHR, 2) void gemm_up8(
    const unsigned short* __restrict__ Ab, const unsigned short* __restrict__ Wt,
    unsigned short* __restrict__ Hb, const int* __restrict__ meta) {
  extern __shared__ char smem[];
  const int* pstart = meta + 16;
  int rt, nt;
  rt_nt_decode(blockIdx.x, NTN_UP, rt, nt);
  int row0 = rt * BM2;
  if (row0 >= pstart[NE]) return;
  int e = 0;
  #pragma unroll
  for (int q = 1; q < NE; ++q) if (row0 >= pstart[q]) e = q;

  int tid = threadIdx.x;
  int wv = tid >> 6, lane = tid & 63;
  int lane16 = lane * 16;

  const char* aTile = (const char*)Ab + (size_t)rt * NKT_UP * TILE_B;
  const char* bTile = (const char*)Wt + (size_t)(e * NTN_UP + nt) * NKT_UP * TILE_B;

  int wm = wv >> 2, wn = wv & 3;
  int hi = lane >> 4;
  int arow_b = (wm * 128 + (lane & 15)) * 16;   // byte offset of frag row base
  int brow_b = (wn * 64 + (lane & 15)) * 16;

  f32x4 acc[8][4] = {};
  bf16x8 bfr[4];

  GEMM_PROLOGUE();
  GEMM_MAIN(NKT_UP);                    // 32 K-tiles

  // epilogue: relu2 -> bf16 -> Hb tiled [rt][kt_dn][c][r][8]
  unsigned short* baseT = Hb + ((size_t)rt * NKT_DN + nt * 4 + wn) * TILE_S
                             + ((lane & 15) >> 3) * 2048 + (lane & 7);
  #pragma unroll
  for (int fm = 0; fm < 8; ++fm) {
    #pragma unroll
    for (int j = 0; j < 4; ++j) {
      int r = wm * 128 + hi * 4 + fm * 16 + j;
      unsigned short* rb = baseT + r * 8;
      #pragma unroll
      for (int fn = 0; fn < 4; ++fn) {
        float v = acc[fm][fn][j];
        v = v > 0.f ? v * v : 0.f;
        rb[fn * 4096] = f2bf(v);        // fn*2 chunks * 2048 shorts
      }
    }
  }
}

// ---------------- GEMM2: ybuf[pair] = h @ down_tiled^T ----------------
__global__ __launch_bounds__(NTHR, 2) void gemm_down8(
    const unsigned short* __restrict__ Hb, const unsigned short* __restrict__ Wt,
    unsigned short* __restrict__ Yb, const int* __restrict__ meta,
    const int* __restrict__ tok) {
  extern __shared__ char smem[];
  const int* pstart = meta + 16;
  int rt, nt;
  rt_nt_decode(blockIdx.x, NTN_DN, rt, nt);
  int row0 = rt * BM2;
  if (row0 >= pstart[NE]) return;
  int e = 0;
  #pragma unroll
  for (int q = 1; q < NE; ++q) if (row0 >= pstart[q]) e = q;

  int tid = threadIdx.x;
  int wv = tid >> 6, lane = tid & 63;
  int lane16 = lane * 16;

  const char* aTile = (const char*)Hb + (size_t)rt * NKT_DN * TILE_B;
  const char* bTile = (const char*)Wt + (size_t)(e * NTN_DN + nt) * NKT_DN * TILE_B;

  int wm = wv >> 2, wn = wv & 3;
  int hi = lane >> 4;
  int arow_b = (wm * 128 + (lane & 15)) * 16;
  int brow_b = (wn * 64 + (lane & 15)) * 16;

  f32x4 acc[8][4] = {};
  bf16x8 bfr[4];

  GEMM_PROLOGUE();
  GEMM_MAIN(NKT_DN);                    // 64 K-tiles

  int crow0 = row0 + wm * 128 + hi * 4;
  int ccol0 = nt * BN2 + wn * 64 + (lane & 15);
  #pragma unroll
  for (int fm = 0; fm < 8; ++fm) {
    #pragma unroll
    for (int j = 0; j < 4; ++j) {
      int p = crow0 + fm * 16 + j;
      int i = tok[p];
      if (i < 0) continue;              // padding row
      unsigned short* dst = Yb + (size_t)i * H_DIM + ccol0;
      #pragma unroll
      for (int fn = 0; fn < 4; ++fn)
        dst[fn * 16] = f2bf(acc[fm][fn][j]);
    }
  }
}

// ---------------- combine: out[t] = w0*y[2t] + w1*y[2t+1] (4 tokens/block) ----------------
__global__ __launch_bounds__(256) void combine(
    const unsigned short* __restrict__ Yb, const float* __restrict__ tkw,
    float* __restrict__ out) {
  int h0 = threadIdx.x * 8;
  #pragma unroll
  for (int tt = 0; tt < 4; ++tt) {
    int t = blockIdx.x * 4 + tt;
    float w0 = tkw[2 * t], w1 = tkw[2 * t + 1];
    bf16x8 ya = *(const bf16x8*)(Yb + (size_t)(2 * t) * H_DIM + h0);
    bf16x8 yb = *(const bf16x8*)(Yb + (size_t)(2 * t + 1) * H_DIM + h0);
    float* dst = out + (size_t)t * H_DIM + h0;
    float4 o0, o1;
    o0.x = w0 * b2f((unsigned short)ya[0]) + w1 * b2f((unsigned short)yb[0]);
    o0.y = w0 * b2f((unsigned short)ya[1]) + w1 * b2f((unsigned short)yb[1]);
    o0.z = w0 * b2f((unsigned short)ya[2]) + w1 * b2f((unsigned short)yb[2]);
    o0.w = w0 * b2f((unsigned short)ya[3]) + w1 * b2f((unsigned short)yb[3]);
    o1.x = w0 * b2f((unsigned short)ya[4]) + w1 * b2f((unsigned short)yb[4]);
    o1.y = w0 * b2f((unsigned short)ya[5]) + w1 * b2f((unsigned short)yb[5]);
    o1.z = w0 * b2f((unsigned short)ya[6]) + w1 * b2f((unsigned short)yb[6]);
    o1.w = w0 * b2f((unsigned short)ya[7]) + w1 * b2f((unsigned short)yb[7]);
    ((float4*)dst)[0] = o0;
    ((float4*)dst)[1] = o1;
  }
}

// ---------------- launch ----------------
extern "C" void kernel_launch(void* const* d_in, const int* in_sizes, int n_in,
                              void* d_out, int out_size, void* d_ws, size_t ws_size,
                              hipStream_t stream) {
  const float* x   = (const float*)d_in[0];
  const int*   tki = (const int*)d_in[1];
  const float* tkw = (const float*)d_in[2];
  const float* up  = (const float*)d_in[3];
  const float* dn  = (const float*)d_in[4];
  float* out = (float*)d_out;
  char* ws = (char*)d_ws;

  unsigned short* ab  = (unsigned short*)(ws + WS_AB);   // tiled A (up)
  unsigned short* wt  = (unsigned short*)(ws + WS_W);    // tiled weights (up->down)
  unsigned short* hb  = (unsigned short*)(ws + WS_H);    // tiled H
  int*            tok = (int*)(ws + WS_TOK);
  unsigned short* yb  = (unsigned short*)(ws + WS_AB);   // Yb overlaps dead Ab
  int*            meta= (int*)(ws + WS_META);

  hipFuncSetAttribute((const void*)gemm_up8,
                      hipFuncAttributeMaxDynamicSharedMemorySize, 131072);
  hipFuncSetAttribute((const void*)gemm_down8,
                      hipFuncAttributeMaxDynamicSharedMemorySize, 131072);

  route_all<<<1, 512, 0, stream>>>(tki, meta, tok);

  gather_tile_x<<<RT_MAX * NKT_UP, 512, 0, stream>>>(x, tok, ab);
  cvt_tile_w<<<NE * NTN_UP * NKT_UP, 512, 0, stream>>>(up, wt, NKT_UP, H_DIM);

  gemm_up8<<<RT_MAX * NTN_UP, NTHR, 131072, stream>>>(ab, wt, hb, meta);

  cvt_tile_w<<<NE * NTN_DN * NKT_DN, 512, 0, stream>>>(dn, wt, NKT_DN, I_DIM);

  gemm_down8<<<RT_MAX * NTN_DN, NTHR, 131072, stream>>>(hb, wt, yb, meta, tok);

  combine<<<T_TOKENS / 4, 256, 0, stream>>>(yb, tkw, out);
}

// Round 10
// 862.338 us; speedup vs baseline: 1.3796x; 1.1696x over previous
//
#include <hip/hip_runtime.h>

// ---------------- problem constants ----------------
#define T_TOKENS 8192
#define H_DIM    2048
#define I_DIM    4096
#define NE       8
#define NPAIR    16384                  // T_TOKENS * TOP_K
#define PADBM    256                    // expert segment padding (= BM of GEMM tiles)
#define PADP     (NPAIR + NE * PADBM)   // 18432 worst-case padded rows
#define RT_MAX   (PADP / PADBM)         // 72 max row tiles (72 = 9*8, XCD-exact)

// 256x256x64 8-phase GEMM geometry
#define BM2 256
#define BN2 256
#define BK2 64
#define NTHR 512
#define NKT_UP (H_DIM / BK2)            // 32
#define NKT_DN (I_DIM / BK2)            // 64
#define NTN_UP (I_DIM / BN2)            // 16
#define NTN_DN (H_DIM / BN2)            // 8
#define TILE_B 32768                    // bytes per 256x64 bf16 operand tile
#define TILE_S 16384                    // shorts per tile

// ---------------- workspace layout (bytes) ----------------
#define WS_AB   0ull
#define WS_W    (WS_AB + (size_t)RT_MAX * NKT_UP * TILE_B)
#define WS_H    (WS_W + (size_t)NE * I_DIM * H_DIM * 2)
#define WS_TOK  (WS_H + (size_t)RT_MAX * NKT_DN * TILE_B)
#define WS_META (WS_TOK + (size_t)PADP * 4)

typedef __attribute__((ext_vector_type(8))) short bf16x8;   // 8 bf16 = 4 VGPRs
typedef __attribute__((ext_vector_type(4))) float f32x4;    // MFMA C/D

__device__ __forceinline__ unsigned short f2bf(float f) {
  union { float f; unsigned u; } a; a.f = f;
  unsigned r = a.u + 0x7fffu + ((a.u >> 16) & 1u);   // RNE
  return (unsigned short)(r >> 16);
}

__device__ __forceinline__ float b2f(unsigned short b) {
  union { unsigned u; float f; } a; a.u = ((unsigned)b) << 16;
  return a.f;
}

__device__ __forceinline__ bf16x8 pack8(float4 a, float4 b) {
  bf16x8 o;
  o[0] = (short)f2bf(a.x); o[1] = (short)f2bf(a.y);
  o[2] = (short)f2bf(a.z); o[3] = (short)f2bf(a.w);
  o[4] = (short)f2bf(b.x); o[5] = (short)f2bf(b.y);
  o[6] = (short)f2bf(b.z); o[7] = (short)f2bf(b.w);
  return o;
}

__device__ __forceinline__ void gload16(const void* g, void* l) {
  __builtin_amdgcn_global_load_lds(
      (const __attribute__((address_space(1))) unsigned int*)g,
      (__attribute__((address_space(3))) unsigned int*)l,
      16, 0, 0);
}

// LDS bank-spread involution for [c][r][16B] tiles: XOR bits 5:6 with bits 7:8.
__device__ __forceinline__ int swz(int a) { return a ^ ((a >> 2) & 0x60); }

// ---------------- routing: single-block count/scan/scatter + tok init ----------------
__global__ __launch_bounds__(512) void route_all(const int* __restrict__ idx,
                                                 int* __restrict__ meta,
                                                 int* __restrict__ tok) {
  __shared__ int cnt[NE], base[NE + 1], cur[NE];
  int t = threadIdx.x;
  if (t < NE) { cnt[t] = 0; cur[t] = 0; }
  for (int i = t; i < PADP; i += 512) tok[i] = -1;   // -1 = padding
  __syncthreads();
  for (int i = t; i < NPAIR; i += 512) atomicAdd(&cnt[idx[i]], 1);
  __syncthreads();
  if (t == 0) {
    int off = 0;
    for (int e = 0; e < NE; ++e) {
      base[e] = off;
      off += ((cnt[e] + PADBM - 1) / PADBM) * PADBM;
    }
    base[NE] = off;
    for (int e = 0; e <= NE; ++e) meta[16 + e] = base[e];
  }
  __syncthreads();
  for (int i = t; i < NPAIR; i += 512) {
    int e = idx[i];
    int pos = base[e] + atomicAdd(&cur[e], 1);
    tok[pos] = i;                       // pair index; token = i>>1 (TOP_K=2)
  }
}

// ---------------- weight fp32 -> tiled bf16 (LDS-staged transpose) ----------------
__global__ __launch_bounds__(512) void cvt_tile_w(
    const float* __restrict__ W, unsigned short* __restrict__ out,
    int NKT, int K) {
  __shared__ float4 ltq[TILE_B / 16];
  char* lt = (char*)ltq;
  int kt = blockIdx.x % NKT, panel = blockIdx.x / NKT;
  int t = threadIdx.x, r = t >> 1, half = t & 1;
  const float* src = W + ((size_t)panel * 256 + r) * K + kt * 64 + half * 32;
  float4 v[8];
  #pragma unroll
  for (int i = 0; i < 8; ++i) v[i] = ((const float4*)src)[i];
  #pragma unroll
  for (int i2 = 0; i2 < 4; ++i2) {
    int c = half * 4 + i2;
    *(bf16x8*)(lt + swz(c * 4096 + r * 16)) = pack8(v[2 * i2], v[2 * i2 + 1]);
  }
  __syncthreads();
  char* dst = (char*)(out + (size_t)blockIdx.x * TILE_S);
  int tb = t * 16;
  #pragma unroll
  for (int i = 0; i < 4; ++i) {
    int o = i * 8192 + tb;
    *(bf16x8*)(dst + o) = *(const bf16x8*)(lt + swz(o));
  }
}

// ---------------- gathered x fp32 -> tiled bf16 A (LDS-staged) ----------------
__global__ __launch_bounds__(512) void gather_tile_x(
    const float* __restrict__ x, const int* __restrict__ tok,
    unsigned short* __restrict__ out) {
  __shared__ float4 ltq[TILE_B / 16];
  char* lt = (char*)ltq;
  int kt = blockIdx.x & (NKT_UP - 1), rt = blockIdx.x >> 5;
  int t = threadIdx.x, r = t >> 1, half = t & 1;
  int v = tok[rt * 256 + r];
  bf16x8 pk[4];
  if (v < 0) {
    #pragma unroll
    for (int i2 = 0; i2 < 4; ++i2) pk[i2] = (bf16x8)0;
  } else {
    const float* src = x + (size_t)(v >> 1) * H_DIM + kt * 64 + half * 32;
    float4 w[8];
    #pragma unroll
    for (int i = 0; i < 8; ++i) w[i] = ((const float4*)src)[i];
    #pragma unroll
    for (int i2 = 0; i2 < 4; ++i2) pk[i2] = pack8(w[2 * i2], w[2 * i2 + 1]);
  }
  #pragma unroll
  for (int i2 = 0; i2 < 4; ++i2) {
    int c = half * 4 + i2;
    *(bf16x8*)(lt + swz(c * 4096 + r * 16)) = pk[i2];
  }
  __syncthreads();
  char* dst = (char*)(out + (size_t)blockIdx.x * TILE_S);   // [rt][kt] order
  int tb = t * 16;
  #pragma unroll
  for (int i = 0; i < 4; ++i) {
    int o = i * 8192 + tb;
    *(bf16x8*)(dst + o) = *(const bf16x8*)(lt + swz(o));
  }
}

// ---------------- 8-phase 256^2 grouped-GEMM core (spread quarter-tile staging) ----------------
// LDS: A dbuf [2][32KB] at 0; B dbuf at 65536.
// Per phase cq: stage quarter q (kc chunks 2q..2q+1, A+B = 2 loads/thread) of
// tile t+1. Waits: vmcnt(4)@c1 -> q2,q3(t) landed before c2's ds_reads;
// vmcnt(4)@c3 -> q0,q1(t+1) landed before next c0's ds_reads.
// In-flight depth <= 8 loads/thread; never drains to 0 in the main loop.

#define STAGE_FULL(KT, BS) do {                                                \
    const char* aT_ = aTile + (size_t)(KT) * TILE_B;                           \
    const char* bT_ = bTile + (size_t)(KT) * TILE_B;                           \
    _Pragma("unroll")                                                          \
    for (int l_ = 0; l_ < 4; ++l_) {                                           \
      int off_ = (l_ * 8 + wv) * 1024 + lane16;                                \
      gload16(aT_ + off_, smem + (BS) * 32768 + off_);                         \
      gload16(bT_ + off_, smem + 65536 + (BS) * 32768 + off_);                 \
    }                                                                          \
  } while (0)

#define STAGE_Q(KT, BS, Q) do {                                                \
    const char* aT_ = aTile + (size_t)(KT) * TILE_B;                           \
    const char* bT_ = bTile + (size_t)(KT) * TILE_B;                           \
    int off_ = ((Q) * 8 + wv) * 1024 + lane16;                                 \
    gload16(aT_ + off_, smem + (BS) * 32768 + off_);                           \
    gload16(bT_ + off_, smem + 65536 + (BS) * 32768 + off_);                   \
  } while (0)

#define PHASE(KS, FH, DO_STAGE, DO_VM) do {                                    \
    bf16x8 af[4];                                                              \
    const char* aB_ = smem + bufc * 32768 + ((KS) * 4 + hi) * 4096;            \
    _Pragma("unroll")                                                          \
    for (int f = 0; f < 4; ++f)                                                \
      af[f] = *(const bf16x8*)(aB_ + arow_b + ((FH) * 4 + f) * 256);           \
    if ((FH) == 0) {                                                           \
      const char* bB_ = smem + 65536 + bufc * 32768 + ((KS) * 4 + hi) * 4096;  \
      _Pragma("unroll")                                                        \
      for (int f = 0; f < 4; ++f)                                              \
        bfr[f] = *(const bf16x8*)(bB_ + brow_b + f * 256);                     \
    }                                                                          \
    DO_STAGE;                                                                  \
    DO_VM;                                                                     \
    __builtin_amdgcn_s_barrier();                                              \
    asm volatile("s_waitcnt lgkmcnt(0)" ::: "memory");                         \
    __builtin_amdgcn_s_setprio(1);                                             \
    _Pragma("unroll")                                                          \
    for (int fm = 0; fm < 4; ++fm)                                             \
      _Pragma("unroll")                                                        \
      for (int fn = 0; fn < 4; ++fn)                                           \
        acc[(FH) * 4 + fm][fn] = __builtin_amdgcn_mfma_f32_16x16x32_bf16(      \
            af[fm], bfr[fn], acc[(FH) * 4 + fm][fn], 0, 0, 0);                 \
    __builtin_amdgcn_s_setprio(0);                                             \
    __builtin_amdgcn_s_barrier();                                              \
  } while (0)

#define GEMM_PROLOGUE()                                                        \
  STAGE_FULL(0, 0);                                                            \
  asm volatile("s_waitcnt vmcnt(4)" ::: "memory");                             \
  __builtin_amdgcn_s_barrier();

#define GEMM_MAIN(NKT)                                                         \
  int bufc = 0;                                                                \
  for (int kt = 0; kt < (NKT); ++kt) {                                         \
    int ktn = (kt + 1 < (NKT)) ? kt + 1 : (NKT) - 1;  /* clamp: uniform counts */\
    int bn_ = bufc ^ 1;                                                        \
    PHASE(0, 0, STAGE_Q(ktn, bn_, 0), (void)0);                                \
    PHASE(0, 1, STAGE_Q(ktn, bn_, 1),                                          \
          asm volatile("s_waitcnt vmcnt(4)" ::: "memory"));                    \
    PHASE(1, 0, STAGE_Q(ktn, bn_, 2), (void)0);                                \
    PHASE(1, 1, STAGE_Q(ktn, bn_, 3),                                          \
          asm volatile("s_waitcnt vmcnt(4)" ::: "memory"));                    \
    bufc ^= 1;                                                                 \
  }

// 2D XCD-locality decode: XCD(bid%8) = (rt%4)*2 + (nt%2).
__device__ __forceinline__ void rt_nt_decode(int bid, int NTN, int& rt, int& nt) {
  int xcd = bid & 7, g = bid >> 3;
  int gh = NTN >> 1;
  int gn = g % gh, gr = g / gh;
  rt = gr * 4 + (xcd >> 1);
  nt = gn * 2 + (xcd & 1);
}

// ---------------- GEMM1: h = relu2(A_tiled @ up_tiled^T), Hb written TILED ----------------
__global__ __launch_bounds__(NTHR, 2) void gemm_up8(
    const unsigned short* __restrict__ Ab, const unsigned short* __restrict__ Wt,
    unsigned short* __restrict__ Hb, const int* __restrict__ meta) {
  extern __shared__ char smem[];
  const int* pstart = meta + 16;
  int rt, nt;
  rt_nt_decode(blockIdx.x, NTN_UP, rt, nt);
  int row0 = rt * BM2;
  if (row0 >= pstart[NE]) return;
  int e = 0;
  #pragma unroll
  for (int q = 1; q < NE; ++q) if (row0 >= pstart[q]) e = q;

  int tid = threadIdx.x;
  int wv = tid >> 6, lane = tid & 63;
  int lane16 = lane * 16;

  const char* aTile = (const char*)Ab + (size_t)rt * NKT_UP * TILE_B;
  const char* bTile = (const char*)Wt + (size_t)(e * NTN_UP + nt) * NKT_UP * TILE_B;

  int wm = wv >> 2, wn = wv & 3;
  int hi = lane >> 4;
  int arow_b = (wm * 128 + (lane & 15)) * 16;   // byte offset of frag row base
  int brow_b = (wn * 64 + (lane & 15)) * 16;

  f32x4 acc[8][4] = {};
  bf16x8 bfr[4];

  GEMM_PROLOGUE();
  GEMM_MAIN(NKT_UP);                    // 32 K-tiles

  // epilogue: relu2 -> bf16 -> Hb tiled [rt][kt_dn][c][r][8]
  unsigned short* baseT = Hb + ((size_t)rt * NKT_DN + nt * 4 + wn) * TILE_S
                             + ((lane & 15) >> 3) * 2048 + (lane & 7);
  #pragma unroll
  for (int fm = 0; fm < 8; ++fm) {
    #pragma unroll
    for (int j = 0; j < 4; ++j) {
      int r = wm * 128 + hi * 4 + fm * 16 + j;
      unsigned short* rb = baseT + r * 8;
      #pragma unroll
      for (int fn = 0; fn < 4; ++fn) {
        float v = acc[fm][fn][j];
        v = v > 0.f ? v * v : 0.f;
        rb[fn * 4096] = f2bf(v);        // fn*2 chunks * 2048 shorts
      }
    }
  }
}

// ---------------- GEMM2: ybuf[pair] = h @ down_tiled^T ----------------
__global__ __launch_bounds__(NTHR, 2) void gemm_down8(
    const unsigned short* __restrict__ Hb, const unsigned short* __restrict__ Wt,
    unsigned short* __restrict__ Yb, const int* __restrict__ meta,
    const int* __restrict__ tok) {
  extern __shared__ char smem[];
  const int* pstart = meta + 16;
  int rt, nt;
  rt_nt_decode(blockIdx.x, NTN_DN, rt, nt);
  int row0 = rt * BM2;
  if (row0 >= pstart[NE]) return;
  int e = 0;
  #pragma unroll
  for (int q = 1; q < NE; ++q) if (row0 >= pstart[q]) e = q;

  int tid = threadIdx.x;
  int wv = tid >> 6, lane = tid & 63;
  int lane16 = lane * 16;

  const char* aTile = (const char*)Hb + (size_t)rt * NKT_DN * TILE_B;
  const char* bTile = (const char*)Wt + (size_t)(e * NTN_DN + nt) * NKT_DN * TILE_B;

  int wm = wv >> 2, wn = wv & 3;
  int hi = lane >> 4;
  int arow_b = (wm * 128 + (lane & 15)) * 16;
  int brow_b = (wn * 64 + (lane & 15)) * 16;

  f32x4 acc[8][4] = {};
  bf16x8 bfr[4];

  GEMM_PROLOGUE();
  GEMM_MAIN(NKT_DN);                    // 64 K-tiles

  int crow0 = row0 + wm * 128 + hi * 4;
  int ccol0 = nt * BN2 + wn * 64 + (lane & 15);
  #pragma unroll
  for (int fm = 0; fm < 8; ++fm) {
    #pragma unroll
    for (int j = 0; j < 4; ++j) {
      int p = crow0 + fm * 16 + j;
      int i = tok[p];
      if (i < 0) continue;              // padding row
      unsigned short* dst = Yb + (size_t)i * H_DIM + ccol0;
      #pragma unroll
      for (int fn = 0; fn < 4; ++fn)
        dst[fn * 16] = f2bf(acc[fm][fn][j]);
    }
  }
}

// ---------------- combine: out[t] = w0*y[2t] + w1*y[2t+1] (4 tokens/block) ----------------
__global__ __launch_bounds__(256) void combine(
    const unsigned short* __restrict__ Yb, const float* __restrict__ tkw,
    float* __restrict__ out) {
  int h0 = threadIdx.x * 8;
  #pragma unroll
  for (int tt = 0; tt < 4; ++tt) {
    int t = blockIdx.x * 4 + tt;
    float w0 = tkw[2 * t], w1 = tkw[2 * t + 1];
    bf16x8 ya = *(const bf16x8*)(Yb + (size_t)(2 * t) * H_DIM + h0);
    bf16x8 yb = *(const bf16x8*)(Yb + (size_t)(2 * t + 1) * H_DIM + h0);
    float* dst = out + (size_t)t * H_DIM + h0;
    float4 o0, o1;
    o0.x = w0 * b2f((unsigned short)ya[0]) + w1 * b2f((unsigned short)yb[0]);
    o0.y = w0 * b2f((unsigned short)ya[1]) + w1 * b2f((unsigned short)yb[1]);
    o0.z = w0 * b2f((unsigned short)ya[2]) + w1 * b2f((unsigned short)yb[2]);
    o0.w = w0 * b2f((unsigned short)ya[3]) + w1 * b2f((unsigned short)yb[3]);
    o1.x = w0 * b2f((unsigned short)ya[4]) + w1 * b2f((unsigned short)yb[4]);
    o1.y = w0 * b2f((unsigned short)ya[5]) + w1 * b2f((unsigned short)yb[5]);
    o1.z = w0 * b2f((unsigned short)ya[6]) + w1 * b2f((unsigned short)yb[6]);
    o1.w = w0 * b2f((unsigned short)ya[7]) + w1 * b2f((unsigned short)yb[7]);
    ((float4*)dst)[0] = o0;
    ((float4*)dst)[1] = o1;
  }
}

// ---------------- launch ----------------
extern "C" void kernel_launch(void* const* d_in, const int* in_sizes, int n_in,
                              void* d_out, int out_size, void* d_ws, size_t ws_size,
                              hipStream_t stream) {
  const float* x   = (const float*)d_in[0];
  const int*   tki = (const int*)d_in[1];
  const float* tkw = (const float*)d_in[2];
  const float* up  = (const float*)d_in[3];
  const float* dn  = (const float*)d_in[4];
  float* out = (float*)d_out;
  char* ws = (char*)d_ws;

  unsigned short* ab  = (unsigned short*)(ws + WS_AB);   // tiled A (up)
  unsigned short* wt  = (unsigned short*)(ws + WS_W);    // tiled weights (up->down)
  unsigned short* hb  = (unsigned short*)(ws + WS_H);    // tiled H
  int*            tok = (int*)(ws + WS_TOK);
  unsigned short* yb  = (unsigned short*)(ws + WS_AB);   // Yb overlaps dead Ab
  int*            meta= (int*)(ws + WS_META);

  hipFuncSetAttribute((const void*)gemm_up8,
                      hipFuncAttributeMaxDynamicSharedMemorySize, 131072);
  hipFuncSetAttribute((const void*)gemm_down8,
                      hipFuncAttributeMaxDynamicSharedMemorySize, 131072);

  route_all<<<1, 512, 0, stream>>>(tki, meta, tok);

  gather_tile_x<<<RT_MAX * NKT_UP, 512, 0, stream>>>(x, tok, ab);
  cvt_tile_w<<<NE * NTN_UP * NKT_UP, 512, 0, stream>>>(up, wt, NKT_UP, H_DIM);

  gemm_up8<<<RT_MAX * NTN_UP, NTHR, 131072, stream>>>(ab, wt, hb, meta);

  cvt_tile_w<<<NE * NTN_DN * NKT_DN, 512, 0, stream>>>(dn, wt, NKT_DN, I_DIM);

  gemm_down8<<<RT_MAX * NTN_DN, NTHR, 131072, stream>>>(hb, wt, yb, meta, tok);

  combine<<<T_TOKENS / 4, 256, 0, stream>>>(yb, tkw, out);
}

// Round 11
// 823.936 us; speedup vs baseline: 1.4439x; 1.0466x over previous
//
#include <hip/hip_runtime.h>

// ---------------- problem constants ----------------
#define T_TOKENS 8192
#define H_DIM    2048
#define I_DIM    4096
#define NE       8
#define NPAIR    16384                  // T_TOKENS * TOP_K
#define PADBM    256                    // expert segment padding (= BM of GEMM tiles)
#define PADP     (NPAIR + NE * PADBM)   // 18432 worst-case padded rows
#define RT_MAX   (PADP / PADBM)         // 72 max row tiles (72 = 9*8, XCD-exact)

// 256x256x64 8-phase GEMM geometry
#define BM2 256
#define BN2 256
#define BK2 64
#define NTHR 512
#define NKT_UP (H_DIM / BK2)            // 32
#define NKT_DN (I_DIM / BK2)            // 64
#define NTN_UP (I_DIM / BN2)            // 16
#define NTN_DN (H_DIM / BN2)            // 8
#define TILE_B 32768                    // bytes per 256x64 bf16 operand tile
#define TILE_S 16384                    // shorts per tile

#define G_UP   (RT_MAX * NTN_UP)        // 1152 gemm_up blocks
#define G_CVTD (NE * NTN_DN * NKT_DN)   // 4096 cvt-down tiles

// ---------------- workspace sizes (bytes) ----------------
#define AB_BYTES  ((size_t)RT_MAX * NKT_UP * TILE_B)   // 75.5 MB (Yb overlaps)
#define W_BYTES   ((size_t)NE * I_DIM * H_DIM * 2)     // 134.2 MB
#define HB_BYTES  ((size_t)RT_MAX * NKT_DN * TILE_B)   // 151.0 MB
#define TOK_BYTES ((size_t)PADP * 4)

typedef __attribute__((ext_vector_type(8))) short bf16x8;   // 8 bf16 = 4 VGPRs
typedef __attribute__((ext_vector_type(4))) float f32x4;    // MFMA C/D

__device__ __forceinline__ unsigned short f2bf(float f) {
  union { float f; unsigned u; } a; a.f = f;
  unsigned r = a.u + 0x7fffu + ((a.u >> 16) & 1u);   // RNE
  return (unsigned short)(r >> 16);
}

__device__ __forceinline__ float b2f(unsigned short b) {
  union { unsigned u; float f; } a; a.u = ((unsigned)b) << 16;
  return a.f;
}

__device__ __forceinline__ bf16x8 pack8(float4 a, float4 b) {
  bf16x8 o;
  o[0] = (short)f2bf(a.x); o[1] = (short)f2bf(a.y);
  o[2] = (short)f2bf(a.z); o[3] = (short)f2bf(a.w);
  o[4] = (short)f2bf(b.x); o[5] = (short)f2bf(b.y);
  o[6] = (short)f2bf(b.z); o[7] = (short)f2bf(b.w);
  return o;
}

__device__ __forceinline__ void gload16(const void* g, void* l) {
  __builtin_amdgcn_global_load_lds(
      (const __attribute__((address_space(1))) unsigned int*)g,
      (__attribute__((address_space(3))) unsigned int*)l,
      16, 0, 0);
}

// LDS bank-spread involution for [c][r][16B] tiles: XOR bits 5:6 with bits 7:8.
__device__ __forceinline__ int swz(int a) { return a ^ ((a >> 2) & 0x60); }

// ---------------- routing: single-block count/scan/scatter + tok init ----------------
__global__ __launch_bounds__(512) void route_all(const int* __restrict__ idx,
                                                 int* __restrict__ meta,
                                                 int* __restrict__ tok) {
  __shared__ int cnt[NE], base[NE + 1], cur[NE];
  int t = threadIdx.x;
  if (t < NE) { cnt[t] = 0; cur[t] = 0; }
  for (int i = t; i < PADP; i += 512) tok[i] = -1;   // -1 = padding
  __syncthreads();
  for (int i = t; i < NPAIR; i += 512) atomicAdd(&cnt[idx[i]], 1);
  __syncthreads();
  if (t == 0) {
    int off = 0;
    for (int e = 0; e < NE; ++e) {
      base[e] = off;
      off += ((cnt[e] + PADBM - 1) / PADBM) * PADBM;
    }
    base[NE] = off;
    for (int e = 0; e <= NE; ++e) meta[16 + e] = base[e];
  }
  __syncthreads();
  for (int i = t; i < NPAIR; i += 512) {
    int e = idx[i];
    int pos = base[e] + atomicAdd(&cur[e], 1);
    tok[pos] = i;                       // pair index; token = i>>1 (TOP_K=2)
  }
}

// ---------------- weight fp32 -> tiled bf16 tile body (LDS-staged transpose) ----------------
__device__ __forceinline__ void cvt_tile_body(
    const float* __restrict__ W, unsigned short* __restrict__ out,
    int tile, int NKT, int K, char* lt) {
  int kt = tile % NKT, panel = tile / NKT;
  int t = threadIdx.x, r = t >> 1, half = t & 1;
  const float* src = W + ((size_t)panel * 256 + r) * K + kt * 64 + half * 32;
  float4 v[8];
  #pragma unroll
  for (int i = 0; i < 8; ++i) v[i] = ((const float4*)src)[i];
  #pragma unroll
  for (int i2 = 0; i2 < 4; ++i2) {
    int c = half * 4 + i2;
    *(bf16x8*)(lt + swz(c * 4096 + r * 16)) = pack8(v[2 * i2], v[2 * i2 + 1]);
  }
  __syncthreads();
  char* dst = (char*)(out + (size_t)tile * TILE_S);
  int tb = t * 16;
  #pragma unroll
  for (int i = 0; i < 4; ++i) {
    int o = i * 8192 + tb;
    *(bf16x8*)(dst + o) = *(const bf16x8*)(lt + swz(o));
  }
}

__global__ __launch_bounds__(512) void cvt_tile_w(
    const float* __restrict__ W, unsigned short* __restrict__ out,
    int NKT, int K) {
  __shared__ float4 ltq[TILE_B / 16];
  cvt_tile_body(W, out, blockIdx.x, NKT, K, (char*)ltq);
}

// ---------------- gathered x fp32 -> tiled bf16 A (LDS-staged) ----------------
__global__ __launch_bounds__(512) void gather_tile_x(
    const float* __restrict__ x, const int* __restrict__ tok,
    unsigned short* __restrict__ out) {
  __shared__ float4 ltq[TILE_B / 16];
  char* lt = (char*)ltq;
  int kt = blockIdx.x & (NKT_UP - 1), rt = blockIdx.x >> 5;
  int t = threadIdx.x, r = t >> 1, half = t & 1;
  int v = tok[rt * 256 + r];
  bf16x8 pk[4];
  if (v < 0) {
    #pragma unroll
    for (int i2 = 0; i2 < 4; ++i2) pk[i2] = (bf16x8)0;
  } else {
    const float* src = x + (size_t)(v >> 1) * H_DIM + kt * 64 + half * 32;
    float4 w[8];
    #pragma unroll
    for (int i = 0; i < 8; ++i) w[i] = ((const float4*)src)[i];
    #pragma unroll
    for (int i2 = 0; i2 < 4; ++i2) pk[i2] = pack8(w[2 * i2], w[2 * i2 + 1]);
  }
  #pragma unroll
  for (int i2 = 0; i2 < 4; ++i2) {
    int c = half * 4 + i2;
    *(bf16x8*)(lt + swz(c * 4096 + r * 16)) = pk[i2];
  }
  __syncthreads();
  char* dst = (char*)(out + (size_t)blockIdx.x * TILE_S);   // [rt][kt] order
  int tb = t * 16;
  #pragma unroll
  for (int i = 0; i < 4; ++i) {
    int o = i * 8192 + tb;
    *(bf16x8*)(dst + o) = *(const bf16x8*)(lt + swz(o));
  }
}

// ---------------- 8-phase 256^2 grouped-GEMM core (spread quarter-tile staging) ----------------
// LDS: A dbuf [2][32KB] at 0; B dbuf at 65536.
// Per phase cq: stage quarter q (kc chunks 2q..2q+1, A+B = 2 loads/thread) of
// tile t+1. Waits: vmcnt(4)@c1 -> q2,q3(t) landed before c2's ds_reads;
// vmcnt(4)@c3 -> q0,q1(t+1) landed before next c0's ds_reads.
// In-flight depth <= 8 loads/thread; never drains to 0 in the main loop.

#define STAGE_FULL(KT, BS) do {                                                \
    const char* aT_ = aTile + (size_t)(KT) * TILE_B;                           \
    const char* bT_ = bTile + (size_t)(KT) * TILE_B;                           \
    _Pragma("unroll")                                                          \
    for (int l_ = 0; l_ < 4; ++l_) {                                           \
      int off_ = (l_ * 8 + wv) * 1024 + lane16;                                \
      gload16(aT_ + off_, smem + (BS) * 32768 + off_);                         \
      gload16(bT_ + off_, smem + 65536 + (BS) * 32768 + off_);                 \
    }                                                                          \
  } while (0)

#define STAGE_Q(KT, BS, Q) do {                                                \
    const char* aT_ = aTile + (size_t)(KT) * TILE_B;                           \
    const char* bT_ = bTile + (size_t)(KT) * TILE_B;                           \
    int off_ = ((Q) * 8 + wv) * 1024 + lane16;                                 \
    gload16(aT_ + off_, smem + (BS) * 32768 + off_);                           \
    gload16(bT_ + off_, smem + 65536 + (BS) * 32768 + off_);                   \
  } while (0)

#define PHASE(KS, FH, DO_STAGE, DO_VM) do {                                    \
    bf16x8 af[4];                                                              \
    const char* aB_ = smem + bufc * 32768 + ((KS) * 4 + hi) * 4096;            \
    _Pragma("unroll")                                                          \
    for (int f = 0; f < 4; ++f)                                                \
      af[f] = *(const bf16x8*)(aB_ + arow_b + ((FH) * 4 + f) * 256);           \
    if ((FH) == 0) {                                                           \
      const char* bB_ = smem + 65536 + bufc * 32768 + ((KS) * 4 + hi) * 4096;  \
      _Pragma("unroll")                                                        \
      for (int f = 0; f < 4; ++f)                                              \
        bfr[f] = *(const bf16x8*)(bB_ + brow_b + f * 256);                     \
    }                                                                          \
    DO_STAGE;                                                                  \
    DO_VM;                                                                     \
    __builtin_amdgcn_s_barrier();                                              \
    asm volatile("s_waitcnt lgkmcnt(0)" ::: "memory");                         \
    __builtin_amdgcn_s_setprio(1);                                             \
    _Pragma("unroll")                                                          \
    for (int fm = 0; fm < 4; ++fm)                                             \
      _Pragma("unroll")                                                        \
      for (int fn = 0; fn < 4; ++fn)                                           \
        acc[(FH) * 4 + fm][fn] = __builtin_amdgcn_mfma_f32_16x16x32_bf16(      \
            af[fm], bfr[fn], acc[(FH) * 4 + fm][fn], 0, 0, 0);                 \
    __builtin_amdgcn_s_setprio(0);                                             \
    __builtin_amdgcn_s_barrier();                                              \
  } while (0)

#define GEMM_PROLOGUE()                                                        \
  STAGE_FULL(0, 0);                                                            \
  asm volatile("s_waitcnt vmcnt(4)" ::: "memory");                             \
  __builtin_amdgcn_s_barrier();

#define GEMM_MAIN(NKT)                                                         \
  int bufc = 0;                                                                \
  for (int kt = 0; kt < (NKT); ++kt) {                                         \
    int ktn = (kt + 1 < (NKT)) ? kt + 1 : (NKT) - 1;  /* clamp: uniform counts */\
    int bn_ = bufc ^ 1;                                                        \
    PHASE(0, 0, STAGE_Q(ktn, bn_, 0), (void)0);                                \
    PHASE(0, 1, STAGE_Q(ktn, bn_, 1),                                          \
          asm volatile("s_waitcnt vmcnt(4)" ::: "memory"));                    \
    PHASE(1, 0, STAGE_Q(ktn, bn_, 2), (void)0);                                \
    PHASE(1, 1, STAGE_Q(ktn, bn_, 3),                                          \
          asm volatile("s_waitcnt vmcnt(4)" ::: "memory"));                    \
    bufc ^= 1;                                                                 \
  }

// 2D XCD-locality decode: XCD(bid%8) = (rt%4)*2 + (nt%2).
__device__ __forceinline__ void rt_nt_decode(int bid, int NTN, int& rt, int& nt) {
  int xcd = bid & 7, g = bid >> 3;
  int gh = NTN >> 1;
  int gn = g % gh, gr = g / gh;
  rt = gr * 4 + (xcd >> 1);
  nt = gn * 2 + (xcd & 1);
}

// ---------------- FUSED GEMM1 + cvt_dn: blocks >= nGemm convert down-weights ----------------
// cvt blocks are dispatched after all gemm blocks -> they fill gemm_up's tail
// rounds (cvt_dn is independent of gemm_up; only gemm_down consumes WtD).
__global__ __launch_bounds__(NTHR, 2) void gemm_up8f(
    const unsigned short* __restrict__ Ab, const unsigned short* __restrict__ WtU,
    unsigned short* __restrict__ Hb, const int* __restrict__ meta,
    const float* __restrict__ dnW, unsigned short* __restrict__ WtD,
    int nGemm) {
  extern __shared__ char smem[];
  if ((int)blockIdx.x >= nGemm) {
    cvt_tile_body(dnW, WtD, (int)blockIdx.x - nGemm, NKT_DN, I_DIM, smem);
    return;
  }
  const int* pstart = meta + 16;
  int rt, nt;
  rt_nt_decode(blockIdx.x, NTN_UP, rt, nt);
  int row0 = rt * BM2;
  if (row0 >= pstart[NE]) return;
  int e = 0;
  #pragma unroll
  for (int q = 1; q < NE; ++q) if (row0 >= pstart[q]) e = q;

  int tid = threadIdx.x;
  int wv = tid >> 6, lane = tid & 63;
  int lane16 = lane * 16;

  const char* aTile = (const char*)Ab + (size_t)rt * NKT_UP * TILE_B;
  const char* bTile = (const char*)WtU + (size_t)(e * NTN_UP + nt) * NKT_UP * TILE_B;

  int wm = wv >> 2, wn = wv & 3;
  int hi = lane >> 4;
  int arow_b = (wm * 128 + (lane & 15)) * 16;   // byte offset of frag row base
  int brow_b = (wn * 64 + (lane & 15)) * 16;

  f32x4 acc[8][4] = {};
  bf16x8 bfr[4];

  GEMM_PROLOGUE();
  GEMM_MAIN(NKT_UP);                    // 32 K-tiles

  // epilogue: relu2 -> bf16 -> Hb tiled [rt][kt_dn][c][r][8]
  unsigned short* baseT = Hb + ((size_t)rt * NKT_DN + nt * 4 + wn) * TILE_S
                             + ((lane & 15) >> 3) * 2048 + (lane & 7);
  #pragma unroll
  for (int fm = 0; fm < 8; ++fm) {
    #pragma unroll
    for (int j = 0; j < 4; ++j) {
      int r = wm * 128 + hi * 4 + fm * 16 + j;
      unsigned short* rb = baseT + r * 8;
      #pragma unroll
      for (int fn = 0; fn < 4; ++fn) {
        float v = acc[fm][fn][j];
        v = v > 0.f ? v * v : 0.f;
        rb[fn * 4096] = f2bf(v);        // fn*2 chunks * 2048 shorts
      }
    }
  }
}

// ---------------- GEMM2: ybuf[pair] = h @ down_tiled^T ----------------
__global__ __launch_bounds__(NTHR, 2) void gemm_down8(
    const unsigned short* __restrict__ Hb, const unsigned short* __restrict__ Wt,
    unsigned short* __restrict__ Yb, const int* __restrict__ meta,
    const int* __restrict__ tok) {
  extern __shared__ char smem[];
  const int* pstart = meta + 16;
  int rt, nt;
  rt_nt_decode(blockIdx.x, NTN_DN, rt, nt);
  int row0 = rt * BM2;
  if (row0 >= pstart[NE]) return;
  int e = 0;
  #pragma unroll
  for (int q = 1; q < NE; ++q) if (row0 >= pstart[q]) e = q;

  int tid = threadIdx.x;
  int wv = tid >> 6, lane = tid & 63;
  int lane16 = lane * 16;

  const char* aTile = (const char*)Hb + (size_t)rt * NKT_DN * TILE_B;
  const char* bTile = (const char*)Wt + (size_t)(e * NTN_DN + nt) * NKT_DN * TILE_B;

  int wm = wv >> 2, wn = wv & 3;
  int hi = lane >> 4;
  int arow_b = (wm * 128 + (lane & 15)) * 16;
  int brow_b = (wn * 64 + (lane & 15)) * 16;

  f32x4 acc[8][4] = {};
  bf16x8 bfr[4];

  GEMM_PROLOGUE();
  GEMM_MAIN(NKT_DN);                    // 64 K-tiles

  int crow0 = row0 + wm * 128 + hi * 4;
  int ccol0 = nt * BN2 + wn * 64 + (lane & 15);
  #pragma unroll
  for (int fm = 0; fm < 8; ++fm) {
    #pragma unroll
    for (int j = 0; j < 4; ++j) {
      int p = crow0 + fm * 16 + j;
      int i = tok[p];
      if (i < 0) continue;              // padding row
      unsigned short* dst = Yb + (size_t)i * H_DIM + ccol0;
      #pragma unroll
      for (int fn = 0; fn < 4; ++fn)
        dst[fn * 16] = f2bf(acc[fm][fn][j]);
    }
  }
}

// ---------------- combine: out[t] = w0*y[2t] + w1*y[2t+1] (4 tokens/block) ----------------
__global__ __launch_bounds__(256) void combine(
    const unsigned short* __restrict__ Yb, const float* __restrict__ tkw,
    float* __restrict__ out) {
  int h0 = threadIdx.x * 8;
  #pragma unroll
  for (int tt = 0; tt < 4; ++tt) {
    int t = blockIdx.x * 4 + tt;
    float w0 = tkw[2 * t], w1 = tkw[2 * t + 1];
    bf16x8 ya = *(const bf16x8*)(Yb + (size_t)(2 * t) * H_DIM + h0);
    bf16x8 yb = *(const bf16x8*)(Yb + (size_t)(2 * t + 1) * H_DIM + h0);
    float* dst = out + (size_t)t * H_DIM + h0;
    float4 o0, o1;
    o0.x = w0 * b2f((unsigned short)ya[0]) + w1 * b2f((unsigned short)yb[0]);
    o0.y = w0 * b2f((unsigned short)ya[1]) + w1 * b2f((unsigned short)yb[1]);
    o0.z = w0 * b2f((unsigned short)ya[2]) + w1 * b2f((unsigned short)yb[2]);
    o0.w = w0 * b2f((unsigned short)ya[3]) + w1 * b2f((unsigned short)yb[3]);
    o1.x = w0 * b2f((unsigned short)ya[4]) + w1 * b2f((unsigned short)yb[4]);
    o1.y = w0 * b2f((unsigned short)ya[5]) + w1 * b2f((unsigned short)yb[5]);
    o1.z = w0 * b2f((unsigned short)ya[6]) + w1 * b2f((unsigned short)yb[6]);
    o1.w = w0 * b2f((unsigned short)ya[7]) + w1 * b2f((unsigned short)yb[7]);
    ((float4*)dst)[0] = o0;
    ((float4*)dst)[1] = o1;
  }
}

// ---------------- launch ----------------
extern "C" void kernel_launch(void* const* d_in, const int* in_sizes, int n_in,
                              void* d_out, int out_size, void* d_ws, size_t ws_size,
                              hipStream_t stream) {
  const float* x   = (const float*)d_in[0];
  const int*   tki = (const int*)d_in[1];
  const float* tkw = (const float*)d_in[2];
  const float* up  = (const float*)d_in[3];
  const float* dn  = (const float*)d_in[4];
  float* out = (float*)d_out;
  char* ws = (char*)d_ws;

  // Fused layout: AB | WtU | WtD | Hb | tok | meta   (~495 MB)
  // Serial layout: AB | Wt(shared) | Hb | tok | meta (~361 MB) — WtD == WtU.
  size_t need_fused = AB_BYTES + 2 * W_BYTES + HB_BYTES + TOK_BYTES + 128;
  bool fused = ws_size >= need_fused;

  unsigned short* ab  = (unsigned short*)ws;
  unsigned short* wtU = (unsigned short*)(ws + AB_BYTES);
  unsigned short* wtD = fused ? (unsigned short*)(ws + AB_BYTES + W_BYTES) : wtU;
  char* pHB = (char*)wtD + W_BYTES;     // works for both layouts
  unsigned short* hb  = (unsigned short*)pHB;
  int*            tok = (int*)(pHB + HB_BYTES);
  int*            meta= (int*)(pHB + HB_BYTES + TOK_BYTES);
  unsigned short* yb  = ab;             // Yb overlaps dead Ab

  hipFuncSetAttribute((const void*)gemm_up8f,
                      hipFuncAttributeMaxDynamicSharedMemorySize, 131072);
  hipFuncSetAttribute((const void*)gemm_down8,
                      hipFuncAttributeMaxDynamicSharedMemorySize, 131072);

  route_all<<<1, 512, 0, stream>>>(tki, meta, tok);

  gather_tile_x<<<RT_MAX * NKT_UP, 512, 0, stream>>>(x, tok, ab);
  cvt_tile_w<<<NE * NTN_UP * NKT_UP, 512, 0, stream>>>(up, wtU, NKT_UP, H_DIM);

  if (fused) {
    // gemm_up blocks first (start immediately); cvt_dn blocks fill the tail.
    gemm_up8f<<<G_UP + G_CVTD, NTHR, 131072, stream>>>(ab, wtU, hb, meta,
                                                       dn, wtD, G_UP);
  } else {
    gemm_up8f<<<G_UP, NTHR, 131072, stream>>>(ab, wtU, hb, meta, dn, wtD, G_UP);
    cvt_tile_w<<<G_CVTD, 512, 0, stream>>>(dn, wtD, NKT_DN, I_DIM);
  }

  gemm_down8<<<RT_MAX * NTN_DN, NTHR, 131072, stream>>>(hb, wtD, yb, meta, tok);

  combine<<<T_TOKENS / 4, 256, 0, stream>>>(yb, tkw, out);
}